// Round 13
// baseline (325.219 us; speedup 1.0000x reference)
//
#include <hip/hip_runtime.h>
#include <hip/hip_bf16.h>
#include <math.h>

// Problem constants
#define T_TOK 32768
#define D_IN  1024
#define H_DIM 512
#define N_E   64
#define TM    32
#define BK    16
#define CAPACITY 1280
#define MARGIN   2e-4f   // fallback f32 path flag margin
#define MARGIN_F 1e-4f   // MFMA 3-product path margin
#define KC1 384

// ws layout (fast path): [h: 64MB][W1p: 2MB][small block]
#define WS_H    0ull
#define WS_W1P  67108864ull
#define WS_OFF  69206016ull
#define WS_NEED 69900000ull
// small block offsets (relative)
#define WS_TI0 0
#define WS_TI1 (4*T_TOK)
#define WS_TW0 (8*T_TOK)
#define WS_TW1 (12*T_TOK)
#define WS_CNT (16*T_TOK)
#define WS_USG (WS_CNT+256)
#define WS_FLAGN (WS_USG+256)
#define WS_ZP  (WS_FLAGN+256)
#define WS_FLAGL (WS_ZP+4096)

typedef __attribute__((ext_vector_type(8))) short short8;
typedef __attribute__((ext_vector_type(4))) float f32x4;

__device__ __forceinline__ float wred64(float v){
#pragma unroll
  for (int m=1;m<64;m<<=1) v += __shfl_xor(v, m, 64);
  return v;
}
__device__ __forceinline__ unsigned short f2bf(float f){
  union { __hip_bfloat16 h; unsigned short u; } cv;
  cv.h = __float2bfloat16(f);
  return cv.u;
}
__device__ __forceinline__ float bf2f(unsigned short u){
  union { __hip_bfloat16 h; unsigned short u; } cv;
  cv.u = u;
  return __bfloat162float(cv.h);
}
// 8 floats -> packed hi uint4 + lo uint4 (bf16 split)
__device__ __forceinline__ void cvt8(const float4 A, const float4 B, uint4 &hi, uint4 &lo){
  unsigned h0=f2bf(A.x),h1=f2bf(A.y),h2=f2bf(A.z),h3=f2bf(A.w);
  unsigned h4=f2bf(B.x),h5=f2bf(B.y),h6=f2bf(B.z),h7=f2bf(B.w);
  unsigned l0=f2bf(A.x-bf2f(h0)),l1=f2bf(A.y-bf2f(h1)),l2=f2bf(A.z-bf2f(h2)),l3=f2bf(A.w-bf2f(h3));
  unsigned l4=f2bf(B.x-bf2f(h4)),l5=f2bf(B.y-bf2f(h5)),l6=f2bf(B.z-bf2f(h6)),l7=f2bf(B.w-bf2f(h7));
  hi = make_uint4(h0|(h1<<16), h2|(h3<<16), h4|(h5<<16), h6|(h7<<16));
  lo = make_uint4(l0|(l1<<16), l2|(l3<<16), l4|(l5<<16), l6|(l7<<16));
}
__device__ __forceinline__ short8 u4s8(uint4 v){
  union { uint4 u; short8 s; } cv; cv.u = v; return cv.s;
}

// ---- numpy pairwise_sum emulation (scalar path), bit-exact ----------------
__device__ __forceinline__ float np_sum8acc(const float* a, int n){
  float r0=a[0],r1=a[1],r2=a[2],r3=a[3],r4=a[4],r5=a[5],r6=a[6],r7=a[7];
  int lim = n - (n & 7);
  int i = 8;
  for (; i < lim; i += 8){
    r0=__fadd_rn(r0,a[i]);   r1=__fadd_rn(r1,a[i+1]);
    r2=__fadd_rn(r2,a[i+2]); r3=__fadd_rn(r3,a[i+3]);
    r4=__fadd_rn(r4,a[i+4]); r5=__fadd_rn(r5,a[i+5]);
    r6=__fadd_rn(r6,a[i+6]); r7=__fadd_rn(r7,a[i+7]);
  }
  float res=__fadd_rn(__fadd_rn(__fadd_rn(r0,r1),__fadd_rn(r2,r3)),
                      __fadd_rn(__fadd_rn(r4,r5),__fadd_rn(r6,r7)));
  for (; i < n; ++i) res=__fadd_rn(res,a[i]);
  return res;
}
__device__ __forceinline__ float np_sum512(const float* a){
  float s01=__fadd_rn(np_sum8acc(a,128),     np_sum8acc(a+128,128));
  float s23=__fadd_rn(np_sum8acc(a+256,128), np_sum8acc(a+384,128));
  return __fadd_rn(s01,s23);
}

// ===========================================================================
// k_pack: W1 f32 [1024][512] -> bf16 hi/lo fragment-packed for 16x16x32 MFMA.
// 512 blocks x 256 threads.
// ===========================================================================
__global__ void k_pack(const float* __restrict__ W1, unsigned short* __restrict__ W1p)
{
  int T = blockIdx.x*256 + threadIdx.x;
  int lane = T & 63;  int rest = T >> 6;
  int nt = rest & 7;  rest >>= 3;
  int s  = rest & 1;  rest >>= 1;
  int ks = rest & 31; int nb = rest >> 5;
  int n  = nb*128 + nt*16 + (lane & 15);
  int kb = ks*32 + (lane >> 4)*8;
  unsigned short o[8];
#pragma unroll
  for (int j=0;j<8;++j){
    float w = W1[(size_t)(kb+j)*H_DIM + n];
    unsigned short hi = f2bf(w);
    o[j] = s ? f2bf(w - bf2f(hi)) : hi;
  }
  size_t base = ((size_t)((((nb*32+ks)*2+s)*8+nt))*512 + (size_t)lane*8);
#pragma unroll
  for (int j=0;j<8;++j) W1p[base+j] = o[j];
}

// ===========================================================================
// k_g1 v4: GEMM1 via MFMA bf16, 3 products. 128x128 tile, BK=32.
// A fragments loaded GLOBAL->REG by the owning wave (each lane's fragment is
// 8 contiguous x floats), cvt8 to bf16 hi/lo in-register UNDER the MFMA
// region. LDS holds only B (16KB single buffer). Inter-barrier region is
// just 4 B ds_writes. bf16 values bit-identical to the LDS round-trip.
// ===========================================================================
__launch_bounds__(256, 2)
__global__ void k_g1(const float* __restrict__ x, const unsigned short* __restrict__ W1p,
                     float* __restrict__ h)
{
  __shared__ __align__(16) unsigned short bF[8192];   // hi@0, lo@4096 (16KB)

  const int b   = blockIdx.x;
  const int nbn = (b >> 3) & 3;
  const int bm  = (b & 7) + (b >> 5) * 8;
  const int t0  = bm * 128;

  const int tid  = threadIdx.x;
  const int lane = tid & 63;
  const int wid  = tid >> 6;
  const int wr4  = (wid >> 1) * 4;
  const int wc4  = (wid & 1) * 4;

  // per-lane A fragment source: row = t0+(wr4+m)*16+(lane&15),
  // k = ks*32 + (lane>>4)*8 + j  (j=0..7 contiguous)
  const int arow = lane & 15;
  const int akof = (lane >> 4) * 8;
  size_t aoff0 = (size_t)(t0 + (wr4+0)*16 + arow)*D_IN + akof;
  size_t aoff1 = (size_t)(t0 + (wr4+1)*16 + arow)*D_IN + akof;
  size_t aoff2 = (size_t)(t0 + (wr4+2)*16 + arow)*D_IN + akof;
  size_t aoff3 = (size_t)(t0 + (wr4+3)*16 + arow)*D_IN + akof;

  f32x4 acc[4][4];
#pragma unroll
  for (int m=0;m<4;++m)
#pragma unroll
    for (int n=0;n<4;++n) acc[m][n] = (f32x4){0.f,0.f,0.f,0.f};

  float4 xa0,xb0, xa1,xb1, xa2,xb2, xa3,xb3;   // raw A for current ks
  uint4  bb0, bb1, bb2, bb3;                   // B staging regs

#define LOADX(KS) do {                                                        \
    int k0_ = (KS)*32;                                                        \
    xa0 = *(const float4*)&x[aoff0 + k0_]; xb0 = *(const float4*)&x[aoff0 + k0_ + 4]; \
    xa1 = *(const float4*)&x[aoff1 + k0_]; xb1 = *(const float4*)&x[aoff1 + k0_ + 4]; \
    xa2 = *(const float4*)&x[aoff2 + k0_]; xb2 = *(const float4*)&x[aoff2 + k0_ + 4]; \
    xa3 = *(const float4*)&x[aoff3 + k0_]; xb3 = *(const float4*)&x[aoff3 + k0_ + 4]; \
  } while(0)

#define LOADB(KS) do {                                                        \
    size_t ch_ = (size_t)(nbn*32 + (KS)) * 8192;                              \
    bb0 = *(const uint4*)&W1p[ch_ + (size_t)(0*256+tid)*8];                   \
    bb1 = *(const uint4*)&W1p[ch_ + (size_t)(1*256+tid)*8];                   \
    bb2 = *(const uint4*)&W1p[ch_ + (size_t)(2*256+tid)*8];                   \
    bb3 = *(const uint4*)&W1p[ch_ + (size_t)(3*256+tid)*8];                   \
  } while(0)

#define WRITEB() do {                                                         \
    *(uint4*)&bF[(0*256+tid)*8] = bb0;                                        \
    *(uint4*)&bF[(1*256+tid)*8] = bb1;                                        \
    *(uint4*)&bF[(2*256+tid)*8] = bb2;                                        \
    *(uint4*)&bF[(3*256+tid)*8] = bb3;                                        \
  } while(0)

  // prologue: bF <- B0; xa/xb <- A(ks=0) in flight
  LOADB(0);
  WRITEB();          // compiler waits vmcnt for bb before ds_write (one-time)
  LOADX(0);
  __syncthreads();   // drains everything: bF=B0 visible, A0 landed

  for (int ks=0; ks<32; ++ks){
    // ---- compute region ----
    // cvt A (data ks) from regs -> fragments (VALU, overlaps MFMA issue)
    short8 ah[4], al[4];
    {
      uint4 hi_, lo_;
      cvt8(xa0, xb0, hi_, lo_); ah[0]=u4s8(hi_); al[0]=u4s8(lo_);
      cvt8(xa1, xb1, hi_, lo_); ah[1]=u4s8(hi_); al[1]=u4s8(lo_);
      cvt8(xa2, xb2, hi_, lo_); ah[2]=u4s8(hi_); al[2]=u4s8(lo_);
      cvt8(xa3, xb3, hi_, lo_); ah[3]=u4s8(hi_); al[3]=u4s8(lo_);
    }
    if (ks+1 < 32){
      LOADX(ks+1);       // raw A for next step; lands by barrier1 drain
      LOADB(ks+1);       // B for next step; lands by barrier1 drain
    }
    short8 bh4[4], bl4[4];
#pragma unroll
    for (int n=0;n<4;++n){
      bh4[n] = *(const short8*)&bF[((wc4+n)*64+lane)*8];
      bl4[n] = *(const short8*)&bF[4096 + ((wc4+n)*64+lane)*8];
    }
#pragma unroll
    for (int m=0;m<4;++m)
#pragma unroll
      for (int n=0;n<4;++n){
        acc[m][n] = __builtin_amdgcn_mfma_f32_16x16x32_bf16(ah[m], bh4[n], acc[m][n], 0,0,0);
        acc[m][n] = __builtin_amdgcn_mfma_f32_16x16x32_bf16(al[m], bh4[n], acc[m][n], 0,0,0);
        acc[m][n] = __builtin_amdgcn_mfma_f32_16x16x32_bf16(ah[m], bl4[n], acc[m][n], 0,0,0);
      }
    __syncthreads();               // bF reads done; loads drained
    if (ks+1 < 32) WRITEB();       // bF <- B(ks+1): 4 ds_writes only
    __syncthreads();               // writes visible
  }
#undef LOADX
#undef LOADB
#undef WRITEB

  // ---- epilogue: C/D layout col=lane&15, row=(lane>>4)*4+r ----
  const int cr = (lane >> 4) * 4;
  const int cc = lane & 15;
#pragma unroll
  for (int m=0;m<4;++m)
#pragma unroll
    for (int n=0;n<4;++n){
      int row0_ = t0 + (wr4+m)*16 + cr;
      int col   = nbn*128 + (wc4+n)*16 + cc;
#pragma unroll
      for (int r=0;r<4;++r)
        h[(size_t)(row0_+r)*H_DIM + col] = acc[m][n][r];
    }
}

// ===========================================================================
// k_ln2: load h, LN + ReLU + GEMM2 + clip + L2norm + softmax + top2 + flags +
// z-partials + top-1 histogram (unflagged only). 32 tokens/block.
// ===========================================================================
__launch_bounds__(256, 3)
__global__ void k_ln2(const float* __restrict__ h,
                      const float* __restrict__ gamma,
                      const float* __restrict__ beta,
                      const float* __restrict__ W2,
                      float* __restrict__ out_rw,
                      int*   __restrict__ ti0, int* __restrict__ ti1,
                      float* __restrict__ tw0, float* __restrict__ tw1,
                      float* __restrict__ zpart,
                      int* __restrict__ flagn, int* __restrict__ flagl,
                      int* __restrict__ counts)
{
  __shared__ __align__(16) char smem[75136];
  __shared__ float zw[4];
  __shared__ int lhist[N_E];
  float* hnT  = (float*)smem;                    // [256][33] = 33792 B
  float* redS = (float*)(smem + 33792);          // [32][33]
  float* redQ = (float*)(smem + 38016);          // [32][33]
  float* sW2  = (float*)(smem + 33792);          // [128][64] = 32768 (overlaps red*)
  float* logitsL = (float*)(smem + 66560);       // [32][65]
  float* muA  = (float*)(smem + 74880);
  float* rsA  = (float*)(smem + 75008);

  const int tid  = threadIdx.x;
  const int wv   = tid >> 6;
  const int lane = tid & 63;
  const int tl   = lane & 7;
  const int cl   = lane >> 3;
  const int cbase = wv*128 + cl*16;
  const int t0 = blockIdx.x * TM;

  if (tid < N_E) lhist[tid] = 0;

  float acc[4][16];
#pragma unroll
  for (int j=0;j<4;++j)
#pragma unroll
    for (int q=0;q<4;++q)
      *(float4*)&acc[j][q*4] = *(const float4*)&h[(size_t)(t0+tl*4+j)*H_DIM + cbase + q*4];

  // ---------------- LayerNorm stats ----------------
  const int g = wv*8 + cl;
#pragma unroll
  for (int j=0;j<4;++j) {
    float s=0.f, qq=0.f;
#pragma unroll
    for (int q=0;q<16;++q){ s += acc[j][q]; qq += acc[j][q]*acc[j][q]; }
    redS[(tl*4+j)*33 + g] = s;
    redQ[(tl*4+j)*33 + g] = qq;
  }
  __syncthreads();
  if (tid < 32) {
    float s=0.f, qq=0.f;
    for (int gg=0; gg<32; ++gg){ s += redS[tid*33+gg]; qq += redQ[tid*33+gg]; }
    float mu = s * (1.f/512.f);
    float var = qq * (1.f/512.f) - mu*mu;
    muA[tid] = mu;
    rsA[tid] = rsqrtf(var + 1e-5f);
  }
  __syncthreads();

  {
    float gmv[16], btv[16];
#pragma unroll
    for (int q=0;q<4;++q){
      *(float4*)&gmv[q*4] = *(const float4*)&gamma[cbase+q*4];
      *(float4*)&btv[q*4] = *(const float4*)&beta[cbase+q*4];
    }
    float mu_[4], rs_[4];
#pragma unroll
    for (int j=0;j<4;++j){ mu_[j]=muA[tl*4+j]; rs_[j]=rsA[tl*4+j]; }
#pragma unroll
    for (int j=0;j<4;++j)
#pragma unroll
      for (int q=0;q<16;++q){
        float hv = (acc[j][q]-mu_[j])*rs_[j]*gmv[q] + btv[q];
        acc[j][q] = fmaxf(hv, 0.f);
      }
  }

  // ---------------- GEMM2 (32KB W2 stages) ----------------
  float plog[8];
#pragma unroll
  for (int i=0;i<8;++i) plog[i]=0.f;
  const int t2 = tid & 31, e0 = (tid >> 5) * 8;

  for (int p=0; p<2; ++p) {
    if ((wv>>1) == p) {
      int ccb = (wv&1)*128 + cl*16;
#pragma unroll
      for (int j=0;j<4;++j)
#pragma unroll
        for (int q=0;q<16;++q)
          hnT[(ccb+q)*33 + tl*4 + j] = acc[j][q];
    }
    __syncthreads();
    for (int ch=0; ch<2; ++ch) {
      {
        const float4* src = (const float4*)(W2 + (size_t)(p*256+ch*128)*N_E);
        float4* dst = (float4*)sW2;
#pragma unroll
        for (int i=0;i<8;++i) dst[tid + 256*i] = src[tid + 256*i];
      }
      __syncthreads();
#pragma unroll 8
      for (int kk=0; kk<128; ++kk) {
        float hh = hnT[(ch*128+kk)*33 + t2];
        float4 wa = *(const float4*)&sW2[kk*64 + e0];
        float4 wb = *(const float4*)&sW2[kk*64 + e0 + 4];
        plog[0]=fmaf(hh,wa.x,plog[0]); plog[1]=fmaf(hh,wa.y,plog[1]);
        plog[2]=fmaf(hh,wa.z,plog[2]); plog[3]=fmaf(hh,wa.w,plog[3]);
        plog[4]=fmaf(hh,wb.x,plog[4]); plog[5]=fmaf(hh,wb.y,plog[5]);
        plog[6]=fmaf(hh,wb.z,plog[6]); plog[7]=fmaf(hh,wb.w,plog[7]);
      }
      __syncthreads();
    }
  }
#pragma unroll
  for (int i=0;i<8;++i) logitsL[t2*65 + e0 + i] = plog[i];
  __syncthreads();

  // ---------------- epilogue: 8 lanes per token ----------------
  const int tE = tid >> 3, jE = tid & 7;
  float v[8];
#pragma unroll
  for (int i=0;i<8;++i){
    float z = logitsL[tE*65 + jE*8 + i];
    v[i] = fminf(fmaxf(z, -50.f), 50.f);
  }
  float ss = 0.f;
#pragma unroll
  for (int i=0;i<8;++i) ss += v[i]*v[i];
#pragma unroll
  for (int m=1;m<8;m<<=1) ss += __shfl_xor(ss, m, 8);
  float scale = 1.f/(fmaxf(sqrtf(ss), 1e-6f) + 1e-6f);
  float ln[8];
#pragma unroll
  for (int i=0;i<8;++i) ln[i] = v[i]*scale;
  float mx = -1e30f;
#pragma unroll
  for (int i=0;i<8;++i) mx = fmaxf(mx, ln[i]);
#pragma unroll
  for (int m=1;m<8;m<<=1) mx = fmaxf(mx, __shfl_xor(mx, m, 8));

  float ex[8], st=0.f, sn=0.f;
#pragma unroll
  for (int i=0;i<8;++i){
    ex[i] = expf((ln[i]-mx)*10.f);
    st += ex[i];
    sn += expf(ln[i]-mx);
  }
#pragma unroll
  for (int m=1;m<8;m<<=1){ st += __shfl_xor(st, m, 8); sn += __shfl_xor(sn, m, 8); }

  float inv_st = 1.f/st;
  float rw[8];
#pragma unroll
  for (int i=0;i<8;++i) rw[i] = ex[i]*inv_st;

  const size_t tok = (size_t)t0 + tE;
  {
    float4* o = (float4*)(out_rw + tok*N_E + jE*8);
    o[0] = make_float4(rw[0],rw[1],rw[2],rw[3]);
    o[1] = make_float4(rw[4],rw[5],rw[6],rw[7]);
  }

  float g1,g2,g3; int i1,i2;
  {
    float bv=-1e30f; int bi=1<<30;
#pragma unroll
    for (int i=0;i<8;++i){ int idx=jE*8+i;
      if (ln[i]>bv || (ln[i]==bv && idx<bi)){ bv=ln[i]; bi=idx; } }
#pragma unroll
    for (int m=1;m<8;m<<=1){ float ov=__shfl_xor(bv,m,8); int oi=__shfl_xor(bi,m,8);
      if (ov>bv || (ov==bv && oi<bi)){ bv=ov; bi=oi; } }
    g1=bv; i1=bi;
    bv=-1e30f; bi=1<<30;
#pragma unroll
    for (int i=0;i<8;++i){ int idx=jE*8+i; if (idx==i1) continue;
      if (ln[i]>bv || (ln[i]==bv && idx<bi)){ bv=ln[i]; bi=idx; } }
#pragma unroll
    for (int m=1;m<8;m<<=1){ float ov=__shfl_xor(bv,m,8); int oi=__shfl_xor(bi,m,8);
      if (ov>bv || (ov==bv && oi<bi)){ bv=ov; bi=oi; } }
    g2=bv; i2=bi;
    bv=-1e30f;
#pragma unroll
    for (int i=0;i<8;++i){ int idx=jE*8+i; if (idx==i1||idx==i2) continue;
      bv = fmaxf(bv, ln[i]); }
#pragma unroll
    for (int m=1;m<8;m<<=1) bv = fmaxf(bv, __shfl_xor(bv,m,8));
    g3=bv;
  }
  if (jE==0){
    float r1 = expf((g1-mx)*10.f)*inv_st;
    float r2 = expf((g2-mx)*10.f)*inv_st;
    float a1 = fminf(fmaxf(r1, 0.001f), 0.8f);
    float a2 = fminf(fmaxf(r2, 0.001f), 0.8f);
    float d  = fmaxf(a1+a2, 1e-6f) + 1e-6f;
    ti0[tok]=i1; ti1[tok]=i2; tw0[tok]=a1/d; tw1[tok]=a2/d;
    bool flg = ((g1-g2) < MARGIN_F) || ((g2-g3) < MARGIN_F);
    if (flg){
      int p = atomicAdd(flagn, 1);
      flagl[p] = (int)tok;
    } else {
      atomicAdd(&lhist[i1], 1);
    }
  }

  float lse = mx + logf(sn);
  float zq = 0.f;
#pragma unroll
  for (int i=0;i<8;++i){
    float lp = fminf(fmaxf(ln[i]-lse, -50.f), 50.f);
    zq += lp*lp;
  }
  zq = wred64(zq);
  if (lane==0) zw[wv] = zq;
  __syncthreads();
  if (tid==0) zpart[blockIdx.x] = zw[0]+zw[1]+zw[2]+zw[3];
  if (tid < N_E && lhist[tid] > 0) atomicAdd(&counts[tid], lhist[tid]);
}

// ===========================================================================
// FALLBACK (round-5, proven): fused f32 k_main
// ===========================================================================
__launch_bounds__(256, 3)
__global__ void k_main(const float* __restrict__ x,
                       const float* __restrict__ W1,
                       const float* __restrict__ gamma,
                       const float* __restrict__ beta,
                       const float* __restrict__ W2,
                       float* __restrict__ out_rw,
                       int*   __restrict__ ti0, int* __restrict__ ti1,
                       float* __restrict__ tw0, float* __restrict__ tw1,
                       float* __restrict__ zpart,
                       int* __restrict__ flagn, int* __restrict__ flagl)
{
  __shared__ __align__(16) char smem[53888];
  __shared__ float zw[4];
  float* sW   = (float*)smem;
  float* sX   = (float*)(smem + 32768);
  float* hnT  = (float*)smem;
  float* redS = (float*)(smem + 36864);
  float* redQ = (float*)(smem + 36864 + 4224);
  float* sW2  = (float*)(smem + 36864);
  float* logitsL = (float*)(smem + 45312);
  float* muA  = (float*)(smem + 53632);
  float* rsA  = (float*)(smem + 53760);

  const int tid  = threadIdx.x;
  const int wv   = tid >> 6;
  const int lane = tid & 63;
  const int tl   = lane & 7;
  const int cl   = lane >> 3;
  const int cbase = wv*128 + cl*16;
  const int t0 = blockIdx.x * TM;

  float acc[4][16];
#pragma unroll
  for (int j=0;j<4;++j)
#pragma unroll
    for (int q=0;q<16;++q) acc[j][q]=0.f;

  for (int k0 = 0; k0 < D_IN; k0 += BK) {
    {
      const float4* srcw = (const float4*)(W1 + (size_t)k0 * H_DIM);
      float4* dstw = (float4*)sW;
#pragma unroll
      for (int i=0;i<8;++i) dstw[tid + 256*i] = srcw[tid + 256*i];
    }
    {
      int e0 = tid*2;
      int tt = e0 >> 4, kk = e0 & 15;
      float2 xv = *(const float2*)&x[(size_t)(t0+tt)*D_IN + k0 + kk];
      sX[kk*36 + tt]     = xv.x;
      sX[(kk+1)*36 + tt] = xv.y;
    }
    __syncthreads();
#pragma unroll
    for (int kk=0; kk<BK; ++kk) {
      float4 a = *(const float4*)&sX[kk*36 + tl*4];
      float b[16];
#pragma unroll
      for (int q=0;q<4;++q) *(float4*)&b[q*4] = *(const float4*)&sW[kk*512 + cbase + q*4];
      float av[4] = {a.x, a.y, a.z, a.w};
#pragma unroll
      for (int j=0;j<4;++j)
#pragma unroll
        for (int q=0;q<16;++q)
          acc[j][q] = fmaf(av[j], b[q], acc[j][q]);
    }
    __syncthreads();
  }

  const int g = wv*8 + cl;
#pragma unroll
  for (int j=0;j<4;++j) {
    float s=0.f, qq=0.f;
#pragma unroll
    for (int q=0;q<16;++q){ s += acc[j][q]; qq += acc[j][q]*acc[j][q]; }
    redS[(tl*4+j)*33 + g] = s;
    redQ[(tl*4+j)*33 + g] = qq;
  }
  __syncthreads();
  if (tid < 32) {
    float s=0.f, qq=0.f;
    for (int gg=0; gg<32; ++gg){ s += redS[tid*33+gg]; qq += redQ[tid*33+gg]; }
    float mu = s * (1.f/512.f);
    float var = qq * (1.f/512.f) - mu*mu;
    muA[tid] = mu;
    rsA[tid] = rsqrtf(var + 1e-5f);
  }
  __syncthreads();

  {
    float gmv[16], btv[16];
#pragma unroll
    for (int q=0;q<4;++q){
      *(float4*)&gmv[q*4] = *(const float4*)&gamma[cbase+q*4];
      *(float4*)&btv[q*4] = *(const float4*)&beta[cbase+q*4];
    }
    float mu_[4], rs_[4];
#pragma unroll
    for (int j=0;j<4;++j){ mu_[j]=muA[tl*4+j]; rs_[j]=rsA[tl*4+j]; }
#pragma unroll
    for (int j=0;j<4;++j)
#pragma unroll
      for (int q=0;q<16;++q){
        float hv = (acc[j][q]-mu_[j])*rs_[j]*gmv[q] + btv[q];
        acc[j][q] = fmaxf(hv, 0.f);
      }
  }

  float plog[8];
#pragma unroll
  for (int i=0;i<8;++i) plog[i]=0.f;
  const int t2 = tid & 31, e0 = (tid >> 5) * 8;

  for (int p=0; p<2; ++p) {
    if ((wv>>1) == p) {
      int ccb = (wv&1)*128 + cl*16;
#pragma unroll
      for (int j=0;j<4;++j)
#pragma unroll
        for (int q=0;q<16;++q)
          hnT[(ccb+q)*33 + tl*4 + j] = acc[j][q];
    }
    __syncthreads();
    for (int ch=0; ch<8; ++ch) {
      {
        const float4* src = (const float4*)(W2 + (size_t)(p*256+ch*32)*N_E);
        float4* dst = (float4*)sW2;
        dst[tid]     = src[tid];
        dst[tid+256] = src[tid+256];
      }
      __syncthreads();
#pragma unroll
      for (int kk=0; kk<32; ++kk) {
        float hh = hnT[(ch*32+kk)*33 + t2];
        float4 wa = *(const float4*)&sW2[kk*64 + e0];
        float4 wb = *(const float4*)&sW2[kk*64 + e0 + 4];
        plog[0]=fmaf(hh,wa.x,plog[0]); plog[1]=fmaf(hh,wa.y,plog[1]);
        plog[2]=fmaf(hh,wa.z,plog[2]); plog[3]=fmaf(hh,wa.w,plog[3]);
        plog[4]=fmaf(hh,wb.x,plog[4]); plog[5]=fmaf(hh,wb.y,plog[5]);
        plog[6]=fmaf(hh,wb.z,plog[6]); plog[7]=fmaf(hh,wb.w,plog[7]);
      }
      __syncthreads();
    }
  }
#pragma unroll
  for (int i=0;i<8;++i) logitsL[t2*65 + e0 + i] = plog[i];
  __syncthreads();

  const int tE = tid >> 3, jE = tid & 7;
  float v[8];
#pragma unroll
  for (int i=0;i<8;++i){
    float z = logitsL[tE*65 + jE*8 + i];
    v[i] = fminf(fmaxf(z, -50.f), 50.f);
  }
  float ss = 0.f;
#pragma unroll
  for (int i=0;i<8;++i) ss += v[i]*v[i];
#pragma unroll
  for (int m=1;m<8;m<<=1) ss += __shfl_xor(ss, m, 8);
  float scale = 1.f/(fmaxf(sqrtf(ss), 1e-6f) + 1e-6f);
  float ln[8];
#pragma unroll
  for (int i=0;i<8;++i) ln[i] = v[i]*scale;
  float mx = -1e30f;
#pragma unroll
  for (int i=0;i<8;++i) mx = fmaxf(mx, ln[i]);
#pragma unroll
  for (int m=1;m<8;m<<=1) mx = fmaxf(mx, __shfl_xor(mx, m, 8));

  float ex[8], st=0.f, sn=0.f;
#pragma unroll
  for (int i=0;i<8;++i){
    ex[i] = expf((ln[i]-mx)*10.f);
    st += ex[i];
    sn += expf(ln[i]-mx);
  }
#pragma unroll
  for (int m=1;m<8;m<<=1){ st += __shfl_xor(st, m, 8); sn += __shfl_xor(sn, m, 8); }

  float inv_st = 1.f/st;
  float rw[8];
#pragma unroll
  for (int i=0;i<8;++i) rw[i] = ex[i]*inv_st;

  const size_t tok = (size_t)t0 + tE;
  {
    float4* o = (float4*)(out_rw + tok*N_E + jE*8);
    o[0] = make_float4(rw[0],rw[1],rw[2],rw[3]);
    o[1] = make_float4(rw[4],rw[5],rw[6],rw[7]);
  }

  float g1,g2,g3; int i1,i2;
  {
    float bv=-1e30f; int bi=1<<30;
#pragma unroll
    for (int i=0;i<8;++i){ int idx=jE*8+i;
      if (ln[i]>bv || (ln[i]==bv && idx<bi)){ bv=ln[i]; bi=idx; } }
#pragma unroll
    for (int m=1;m<8;m<<=1){ float ov=__shfl_xor(bv,m,8); int oi=__shfl_xor(bi,m,8);
      if (ov>bv || (ov==bv && oi<bi)){ bv=ov; bi=oi; } }
    g1=bv; i1=bi;
    bv=-1e30f; bi=1<<30;
#pragma unroll
    for (int i=0;i<8;++i){ int idx=jE*8+i; if (idx==i1) continue;
      if (ln[i]>bv || (ln[i]==bv && idx<bi)){ bv=ln[i]; bi=idx; } }
#pragma unroll
    for (int m=1;m<8;m<<=1){ float ov=__shfl_xor(bv,m,8); int oi=__shfl_xor(bi,m,8);
      if (ov>bv || (ov==bv && oi<bi)){ bv=ov; bi=oi; } }
    g2=bv; i2=bi;
    bv=-1e30f;
#pragma unroll
    for (int i=0;i<8;++i){ int idx=jE*8+i; if (idx==i1||idx==i2) continue;
      bv = fmaxf(bv, ln[i]); }
#pragma unroll
    for (int m=1;m<8;m<<=1) bv = fmaxf(bv, __shfl_xor(bv,m,8));
    g3=bv;
  }
  if (jE==0){
    float r1 = expf((g1-mx)*10.f)*inv_st;
    float r2 = expf((g2-mx)*10.f)*inv_st;
    float a1 = fminf(fmaxf(r1, 0.001f), 0.8f);
    float a2 = fminf(fmaxf(r2, 0.001f), 0.8f);
    float d  = fmaxf(a1+a2, 1e-6f) + 1e-6f;
    ti0[tok]=i1; ti1[tok]=i2; tw0[tok]=a1/d; tw1[tok]=a2/d;
    if ((g1-g2) < MARGIN || (g2-g3) < MARGIN){
      int p = atomicAdd(flagn, 1);
      flagl[p] = (int)tok;
    }
  }

  float lse = mx + logf(sn);
  float zq = 0.f;
#pragma unroll
  for (int i=0;i<8;++i){
    float lp = fminf(fmaxf(ln[i]-lse, -50.f), 50.f);
    zq += lp*lp;
  }
  zq = wred64(zq);
  if (lane==0) zw[wv] = zq;
  __syncthreads();
  if (tid==0) zpart[blockIdx.x] = zw[0]+zw[1]+zw[2]+zw[3];
}

// ===========================================================================
// np-f32 emulator for flagged tokens — LDS-staged (round-8 proven).
// ===========================================================================
__launch_bounds__(256, 1)
__global__ void k_fix(const float* __restrict__ x, const float* __restrict__ W1,
                      const float* __restrict__ gamma, const float* __restrict__ beta,
                      const float* __restrict__ W2,
                      const int* __restrict__ flagl, const int* __restrict__ flagn,
                      int* __restrict__ ti0, int* __restrict__ ti1,
                      float* __restrict__ tw0, float* __restrict__ tw1,
                      int* __restrict__ counts, int do_count)
{
  __shared__ __align__(16) float sx[D_IN];
  __shared__ __align__(16) float sW[32*H_DIM];
  __shared__ float hS[H_DIM], sqS[H_DIM], hnS[H_DIM];
  __shared__ float sq64[N_E], eS[N_E];
  __shared__ float sc[4];
  const int tid = threadIdx.x;
  const int nf = *flagn;
  for (int it = blockIdx.x; it < nf; it += gridDim.x) {
    const int tok = flagl[it];
    ((float4*)sx)[tid] = ((const float4*)(x + (size_t)tok*D_IN))[tid];
    const int c0 = tid*2;
    float h0=0.f, h1=0.f, a0=0.f, a1=0.f;
    for (int kb=0; kb<D_IN; kb+=32){
      __syncthreads();
      const float4* src = (const float4*)(W1 + (size_t)kb*H_DIM);
#pragma unroll
      for (int i=0;i<16;++i) ((float4*)sW)[tid + 256*i] = src[tid + 256*i];
      __syncthreads();
#pragma unroll 8
      for (int k=0;k<32;++k){
        float xk = sx[kb+k];
        float2 w = *(const float2*)&sW[k*H_DIM + c0];
        a0 = fmaf(xk, w.x, a0); a1 = fmaf(xk, w.y, a1);
      }
      int ke = kb + 32;
      if (ke == 384){ h0 = a0; h1 = a1; a0 = 0.f; a1 = 0.f; }
      else if (ke == 768 || ke == 1024){
        h0 = __fadd_rn(h0, a0); h1 = __fadd_rn(h1, a1); a0 = 0.f; a1 = 0.f;
      }
    }
    hS[c0]=h0; hS[c0+1]=h1;
    __syncthreads();
    if (tid==0) sc[0] = __fdiv_rn(np_sum512(hS), 512.0f);
    __syncthreads();
    float mu = sc[0];
    float d0 = __fsub_rn(h0, mu), d1 = __fsub_rn(h1, mu);
    sqS[c0]   = __fmul_rn(d0,d0);
    sqS[c0+1] = __fmul_rn(d1,d1);
    __syncthreads();
    if (tid==0){
      float var = __fdiv_rn(np_sum512(sqS), 512.0f);
      sc[1] = __fsqrt_rn(__fadd_rn(var, 1e-5f));
    }
    __syncthreads();
    float den = sc[1];
    float2 gm = *(const float2*)&gamma[c0];
    float2 bt = *(const float2*)&beta[c0];
    hnS[c0]   = fmaxf(__fadd_rn(__fmul_rn(__fdiv_rn(d0,den), gm.x), bt.x), 0.f);
    hnS[c0+1] = fmaxf(__fadd_rn(__fmul_rn(__fdiv_rn(d1,den), gm.y), bt.y), 0.f);
    float b0=0.f, b1=0.f;
    for (int half=0; half<2; ++half){
      __syncthreads();
      const float4* src = (const float4*)(W2 + (size_t)(half*256)*N_E);
#pragma unroll
      for (int i=0;i<16;++i) ((float4*)sW)[tid + 256*i] = src[tid + 256*i];
      __syncthreads();
      if (tid < N_E){
        if (half==0){
#pragma unroll 8
          for (int c=0;c<256;++c) b0 = fmaf(hnS[c], sW[c*N_E+tid], b0);
        } else {
#pragma unroll 8
          for (int c=256;c<KC1;++c) b0 = fmaf(hnS[c], sW[(c-256)*N_E+tid], b0);
#pragma unroll 8
          for (int c=KC1;c<H_DIM;++c) b1 = fmaf(hnS[c], sW[(c-256)*N_E+tid], b1);
        }
      }
    }
    float lgf = 0.f;
    if (tid < N_E){
      lgf = __fadd_rn(b0, b1);
      lgf = fminf(fmaxf(lgf, -50.f), 50.f);
      sq64[tid] = __fmul_rn(lgf, lgf);
    }
    __syncthreads();
    if (tid==0){
      float nrm = __fsqrt_rn(np_sum8acc(sq64, 64));
      sc[2] = __fadd_rn(fmaxf(nrm, 1e-6f), 1e-6f);
    }
    __syncthreads();
    if (tid < N_E){
      float nl = __fdiv_rn(lgf, sc[2]);
      float z  = __fdiv_rn(nl, 0.1f);
      float mz = z;
#pragma unroll
      for (int m=1;m<64;m<<=1) mz = fmaxf(mz, __shfl_xor(mz,m,64));
      eS[tid] = expf(__fsub_rn(z, mz));
    }
    __syncthreads();
    if (tid==0) sc[3] = np_sum8acc(eS, 64);
    __syncthreads();
    if (tid < N_E){
      float rw = __fdiv_rn(eS[tid], sc[3]);
      float bv = rw; int bi = tid;
#pragma unroll
      for (int m=1;m<64;m<<=1){ float ov=__shfl_xor(bv,m,64); int oi=__shfl_xor(bi,m,64);
        if (ov>bv || (ov==bv && oi<bi)){ bv=ov; bi=oi; } }
      float R1=bv; int I1=bi;
      bv = (tid==I1) ? -1.f : rw; bi = (tid==I1) ? (1<<30) : tid;
#pragma unroll
      for (int m=1;m<64;m<<=1){ float ov=__shfl_xor(bv,m,64); int oi=__shfl_xor(bi,m,64);
        if (ov>bv || (ov==bv && oi<bi)){ bv=ov; bi=oi; } }
      float R2=bv; int I2=bi;
      if (tid==0){
        float A1 = fminf(fmaxf(R1, 0.001f), 0.8f);
        float A2 = fminf(fmaxf(R2, 0.001f), 0.8f);
        float dd = __fadd_rn(fmaxf(__fadd_rn(A1,A2), 1e-6f), 1e-6f);
        ti0[tok]=I1; ti1[tok]=I2;
        tw0[tok]=__fdiv_rn(A1,dd); tw1[tok]=__fdiv_rn(A2,dd);
        if (do_count) atomicAdd(&counts[I1], 1);
      }
    }
    __syncthreads();
  }
}

// ---------------------------------------------------------------------------
__global__ void k_hist(const int* __restrict__ ti0, int* __restrict__ counts)
{
  __shared__ int lh[N_E];
  int tid = threadIdx.x;
  if (tid < N_E) lh[tid] = 0;
  __syncthreads();
  int i = blockIdx.x*256 + tid;
  atomicAdd(&lh[ti0[i]], 1);
  __syncthreads();
  if (tid < N_E) atomicAdd(&counts[tid], lh[tid]);
}

__global__ void k_dispatch(const int* __restrict__ ti0, const int* __restrict__ ti1,
                           const float* __restrict__ tw0, const float* __restrict__ tw1,
                           const int* __restrict__ counts,
                           float* __restrict__ out_ndm, float* __restrict__ usage)
{
  __shared__ float lus[N_E];
  int tid = threadIdx.x;
  if (tid < N_E) lus[tid] = 0.f;
  __syncthreads();
  int gid = blockIdx.x*256 + tid;
  size_t tok = gid >> 3;
  int jE = gid & 7;
  int i0 = ti0[tok], i1 = ti1[tok];
  float w0 = tw0[tok], w1 = tw1[tok];
  float w1m = (counts[i1] < CAPACITY) ? w1 : 0.f;
  float inv = 1.f / fmaxf(w0 + w1m, 1e-12f);
  float vv[8];
#pragma unroll
  for (int i=0;i<8;++i){
    int e = jE*8+i;
    vv[i] = (e==i0) ? w0*inv : (e==i1) ? w1m*inv : 0.f;
  }
  float4* o = (float4*)(out_ndm + tok*N_E + jE*8);
  o[0] = make_float4(vv[0],vv[1],vv[2],vv[3]);
  o[1] = make_float4(vv[4],vv[5],vv[6],vv[7]);
  if (jE==0){
    atomicAdd(&lus[i0], w0*inv);
    atomicAdd(&lus[i1], w1m*inv);
  }
  __syncthreads();
  if (tid < N_E) atomicAdd(&usage[tid], lus[tid]);
}

__global__ void k_final(const float* __restrict__ usage, const float* __restrict__ zpart,
                        float* __restrict__ out_loss)
{
  int e = threadIdx.x;
  float u = usage[e];
  float usum = wred64(u);
  float un = u / (fmaxf(usum, 1e-6f) + 1e-6f);
  un = fminf(fmaxf(un, 1e-6f), 1.0f);
  const float target = 1.0f/64.0f;
  float term = target * (logf(target) - logf(un + 1e-6f));
  float kl = wred64(term) * (1.0f/64.0f);
  kl = fminf(kl, 100.f);
  float zs = 0.f;
  for (int i=e; i<1024; i+=64) zs += zpart[i];
  zs = wred64(zs);
  float z = fminf(zs / (float)(T_TOK*N_E), 100.f);
  float loss = 1e-4f*z + 1e-4f*kl;
  if (isnan(loss) || isinf(loss)) loss = 0.1f;
  if (e==0) out_loss[0] = loss;
}

extern "C" void kernel_launch(void* const* d_in, const int* in_sizes, int n_in,
                              void* d_out, int out_size, void* d_ws, size_t ws_size,
                              hipStream_t stream) {
  const float* x     = (const float*)d_in[0];
  const float* W1    = (const float*)d_in[1];
  const float* gamma = (const float*)d_in[2];
  const float* beta  = (const float*)d_in[3];
  const float* W2    = (const float*)d_in[4];
  float* out = (float*)d_out;

  const bool fast = (ws_size >= WS_NEED);
  char* ws = (char*)d_ws;
  char* sb = ws + (fast ? WS_OFF : 0ull);
  int*   ti0   = (int*)(sb + WS_TI0);
  int*   ti1   = (int*)(sb + WS_TI1);
  float* tw0   = (float*)(sb + WS_TW0);
  float* tw1   = (float*)(sb + WS_TW1);
  int*   cnts  = (int*)(sb + WS_CNT);
  float* usage = (float*)(sb + WS_USG);
  int*   flagn = (int*)(sb + WS_FLAGN);
  float* zpart = (float*)(sb + WS_ZP);
  int*   flagl = (int*)(sb + WS_FLAGL);

  hipMemsetAsync(sb + WS_CNT, 0, 768, stream);

  float* out_rw   = out;
  float* out_ndm  = out + (size_t)T_TOK*N_E;
  float* out_loss = out + 2ull*T_TOK*N_E;

  if (fast) {
    float* hbuf = (float*)(ws + WS_H);
    unsigned short* W1p = (unsigned short*)(ws + WS_W1P);
    k_pack<<<512, 256, 0, stream>>>(W1, W1p);
    k_g1<<<1024, 256, 0, stream>>>(x, W1p, hbuf);
    k_ln2<<<T_TOK/TM, 256, 0, stream>>>(hbuf, gamma, beta, W2,
                                        out_rw, ti0, ti1, tw0, tw1, zpart,
                                        flagn, flagl, cnts);
    k_fix<<<1024, 256, 0, stream>>>(x, W1, gamma, beta, W2, flagl, flagn,
                                    ti0, ti1, tw0, tw1, cnts, 1);
  } else {
    k_main<<<T_TOK/TM, 256, 0, stream>>>(x, W1, gamma, beta, W2,
                                         out_rw, ti0, ti1, tw0, tw1, zpart,
                                         flagn, flagl);
    k_fix<<<1024, 256, 0, stream>>>(x, W1, gamma, beta, W2, flagl, flagn,
                                    ti0, ti1, tw0, tw1, cnts, 0);
    k_hist<<<T_TOK/256, 256, 0, stream>>>(ti0, cnts);
  }
  k_dispatch<<<(T_TOK*8)/256, 256, 0, stream>>>(ti0, ti1, tw0, tw1, cnts,
                                                out_ndm, usage);
  k_final<<<1, 64, 0, stream>>>(usage, zpart, out_loss);
}

// Round 14
// 296.781 us; speedup vs baseline: 1.0958x; 1.0958x over previous
//
#include <hip/hip_runtime.h>
#include <hip/hip_bf16.h>
#include <math.h>

// Problem constants
#define T_TOK 32768
#define D_IN  1024
#define H_DIM 512
#define N_E   64
#define TM    32
#define BK    16
#define CAPACITY 1280
#define MARGIN   2e-4f   // fallback f32 path flag margin
#define MARGIN_F 1e-4f   // MFMA 3-product path margin
#define KC1 384

// ws layout (fast path): [h: 64MB][W1p: 2MB][small block]
#define WS_H    0ull
#define WS_W1P  67108864ull
#define WS_OFF  69206016ull
#define WS_NEED 69900000ull
// small block offsets (relative)
#define WS_TI0 0
#define WS_TI1 (4*T_TOK)
#define WS_TW0 (8*T_TOK)
#define WS_TW1 (12*T_TOK)
#define WS_CNT (16*T_TOK)
#define WS_USG (WS_CNT+256)
#define WS_FLAGN (WS_USG+256)
#define WS_ZP  (WS_FLAGN+256)
#define WS_FLAGL (WS_ZP+4096)

typedef __attribute__((ext_vector_type(8))) short short8;
typedef __attribute__((ext_vector_type(4))) float f32x4;

__device__ __forceinline__ float wred64(float v){
#pragma unroll
  for (int m=1;m<64;m<<=1) v += __shfl_xor(v, m, 64);
  return v;
}
__device__ __forceinline__ unsigned short f2bf(float f){
  union { __hip_bfloat16 h; unsigned short u; } cv;
  cv.h = __float2bfloat16(f);
  return cv.u;
}
__device__ __forceinline__ float bf2f(unsigned short u){
  union { __hip_bfloat16 h; unsigned short u; } cv;
  cv.u = u;
  return __bfloat162float(cv.h);
}
// 8 floats -> packed hi uint4 + lo uint4 (bf16 split)
__device__ __forceinline__ void cvt8(const float4 A, const float4 B, uint4 &hi, uint4 &lo){
  unsigned h0=f2bf(A.x),h1=f2bf(A.y),h2=f2bf(A.z),h3=f2bf(A.w);
  unsigned h4=f2bf(B.x),h5=f2bf(B.y),h6=f2bf(B.z),h7=f2bf(B.w);
  unsigned l0=f2bf(A.x-bf2f(h0)),l1=f2bf(A.y-bf2f(h1)),l2=f2bf(A.z-bf2f(h2)),l3=f2bf(A.w-bf2f(h3));
  unsigned l4=f2bf(B.x-bf2f(h4)),l5=f2bf(B.y-bf2f(h5)),l6=f2bf(B.z-bf2f(h6)),l7=f2bf(B.w-bf2f(h7));
  hi = make_uint4(h0|(h1<<16), h2|(h3<<16), h4|(h5<<16), h6|(h7<<16));
  lo = make_uint4(l0|(l1<<16), l2|(l3<<16), l4|(l5<<16), l6|(l7<<16));
}

// ---- numpy pairwise_sum emulation (scalar path), bit-exact ----------------
__device__ __forceinline__ float np_sum8acc(const float* a, int n){
  float r0=a[0],r1=a[1],r2=a[2],r3=a[3],r4=a[4],r5=a[5],r6=a[6],r7=a[7];
  int lim = n - (n & 7);
  int i = 8;
  for (; i < lim; i += 8){
    r0=__fadd_rn(r0,a[i]);   r1=__fadd_rn(r1,a[i+1]);
    r2=__fadd_rn(r2,a[i+2]); r3=__fadd_rn(r3,a[i+3]);
    r4=__fadd_rn(r4,a[i+4]); r5=__fadd_rn(r5,a[i+5]);
    r6=__fadd_rn(r6,a[i+6]); r7=__fadd_rn(r7,a[i+7]);
  }
  float res=__fadd_rn(__fadd_rn(__fadd_rn(r0,r1),__fadd_rn(r2,r3)),
                      __fadd_rn(__fadd_rn(r4,r5),__fadd_rn(r6,r7)));
  for (; i < n; ++i) res=__fadd_rn(res,a[i]);
  return res;
}
__device__ __forceinline__ float np_sum512(const float* a){
  float s01=__fadd_rn(np_sum8acc(a,128),     np_sum8acc(a+128,128));
  float s23=__fadd_rn(np_sum8acc(a+256,128), np_sum8acc(a+384,128));
  return __fadd_rn(s01,s23);
}

// ===========================================================================
// k_pack: W1 f32 [1024][512] -> bf16 hi/lo fragment-packed for 16x16x32 MFMA.
// 512 blocks x 256 threads.
// ===========================================================================
__global__ void k_pack(const float* __restrict__ W1, unsigned short* __restrict__ W1p)
{
  int T = blockIdx.x*256 + threadIdx.x;
  int lane = T & 63;  int rest = T >> 6;
  int nt = rest & 7;  rest >>= 3;
  int s  = rest & 1;  rest >>= 1;
  int ks = rest & 31; int nb = rest >> 5;
  int n  = nb*128 + nt*16 + (lane & 15);
  int kb = ks*32 + (lane >> 4)*8;
  unsigned short o[8];
#pragma unroll
  for (int j=0;j<8;++j){
    float w = W1[(size_t)(kb+j)*H_DIM + n];
    unsigned short hi = f2bf(w);
    o[j] = s ? f2bf(w - bf2f(hi)) : hi;
  }
  size_t base = ((size_t)((((nb*32+ks)*2+s)*8+nt))*512 + (size_t)lane*8);
#pragma unroll
  for (int j=0;j<8;++j) W1p[base+j] = o[j];
}

// ===========================================================================
// k_g1 v5: round-12 structure (A+B staged via LDS, coalesced global loads,
// 32KB single buffer, 2 barriers/iter) + PING-PONG staging regs so global
// loads are ISSUED IN THE COMPUTE REGION (drained at barrier1, overlapped by
// MFMA+LDS work) instead of in the write region where round-12's barrier2
// vmcnt(0) drain serialized the full L2 latency every iteration.
// Even iter: load setB(ks+2) at compute-top, write setA(ks+1) after barrier1.
// Odd iter: swap. Explicit reg names (no runtime-indexed arrays).
// ===========================================================================
__launch_bounds__(256, 2)
__global__ void k_g1(const float* __restrict__ x, const unsigned short* __restrict__ W1p,
                     float* __restrict__ h)
{
  __shared__ __align__(16) unsigned short aF[8192];   // hi [512 slots][8] @0, lo @4096
  __shared__ __align__(16) unsigned short bF[8192];   // hi @0, lo @4096

  const int b   = blockIdx.x;
  const int nbn = (b >> 3) & 3;
  const int bm  = (b & 7) + (b >> 5) * 8;
  const int t0  = bm * 128;

  const int tid  = threadIdx.x;
  const int lane = tid & 63;
  const int wid  = tid >> 6;
  const int wr4  = (wid >> 1) * 4;
  const int wc4  = (wid & 1) * 4;

  // A slots: s in {tid, tid+256}; row(s) = (s>>6)*16 + (s&15), g(s) = (s>>4)&3
  const int s0 = tid, s1 = tid + 256;
  const int row0 = ((s0>>6)<<4) + (s0&15);  const int g0 = (s0>>4)&3;
  const int row1 = ((s1>>6)<<4) + (s1&15);  const int g1 = (s1>>4)&3;
  const size_t xoff0 = (size_t)(t0+row0)*D_IN + g0*8;
  const size_t xoff1 = (size_t)(t0+row1)*D_IN + g1*8;

  f32x4 acc[4][4];
#pragma unroll
  for (int m=0;m<4;++m)
#pragma unroll
    for (int n=0;n<4;++n) acc[m][n] = (f32x4){0.f,0.f,0.f,0.f};

  // ping-pong staging register sets
  float4 xA0,xA1,xA2,xA3;  uint4 bA0,bA1,bA2,bA3;   // set A
  float4 xB0,xB1,xB2,xB3;  uint4 bB0,bB1,bB2,bB3;   // set B

#define LOADG_A(KS) do {                                                      \
    int k0_ = (KS)*32;                                                        \
    xA0 = *(const float4*)&x[xoff0 + k0_];                                    \
    xA1 = *(const float4*)&x[xoff0 + k0_ + 4];                                \
    xA2 = *(const float4*)&x[xoff1 + k0_];                                    \
    xA3 = *(const float4*)&x[xoff1 + k0_ + 4];                                \
    size_t ch_ = (size_t)(nbn*32 + (KS)) * 8192;                              \
    bA0 = *(const uint4*)&W1p[ch_ + (size_t)(0*256+tid)*8];                   \
    bA1 = *(const uint4*)&W1p[ch_ + (size_t)(1*256+tid)*8];                   \
    bA2 = *(const uint4*)&W1p[ch_ + (size_t)(2*256+tid)*8];                   \
    bA3 = *(const uint4*)&W1p[ch_ + (size_t)(3*256+tid)*8];                   \
  } while(0)

#define LOADG_B(KS) do {                                                      \
    int k0_ = (KS)*32;                                                        \
    xB0 = *(const float4*)&x[xoff0 + k0_];                                    \
    xB1 = *(const float4*)&x[xoff0 + k0_ + 4];                                \
    xB2 = *(const float4*)&x[xoff1 + k0_];                                    \
    xB3 = *(const float4*)&x[xoff1 + k0_ + 4];                                \
    size_t ch_ = (size_t)(nbn*32 + (KS)) * 8192;                              \
    bB0 = *(const uint4*)&W1p[ch_ + (size_t)(0*256+tid)*8];                   \
    bB1 = *(const uint4*)&W1p[ch_ + (size_t)(1*256+tid)*8];                   \
    bB2 = *(const uint4*)&W1p[ch_ + (size_t)(2*256+tid)*8];                   \
    bB3 = *(const uint4*)&W1p[ch_ + (size_t)(3*256+tid)*8];                   \
  } while(0)

#define WRITE_A() do {                                                        \
    uint4 hi_, lo_;                                                           \
    cvt8(xA0, xA1, hi_, lo_);                                                 \
    *(uint4*)&aF[s0*8]        = hi_;                                          \
    *(uint4*)&aF[4096 + s0*8] = lo_;                                          \
    cvt8(xA2, xA3, hi_, lo_);                                                 \
    *(uint4*)&aF[s1*8]        = hi_;                                          \
    *(uint4*)&aF[4096 + s1*8] = lo_;                                          \
    *(uint4*)&bF[(0*256+tid)*8] = bA0;                                        \
    *(uint4*)&bF[(1*256+tid)*8] = bA1;                                        \
    *(uint4*)&bF[(2*256+tid)*8] = bA2;                                        \
    *(uint4*)&bF[(3*256+tid)*8] = bA3;                                        \
  } while(0)

#define WRITE_B() do {                                                        \
    uint4 hi_, lo_;                                                           \
    cvt8(xB0, xB1, hi_, lo_);                                                 \
    *(uint4*)&aF[s0*8]        = hi_;                                          \
    *(uint4*)&aF[4096 + s0*8] = lo_;                                          \
    cvt8(xB2, xB3, hi_, lo_);                                                 \
    *(uint4*)&aF[s1*8]        = hi_;                                          \
    *(uint4*)&aF[4096 + s1*8] = lo_;                                          \
    *(uint4*)&bF[(0*256+tid)*8] = bB0;                                        \
    *(uint4*)&bF[(1*256+tid)*8] = bB1;                                        \
    *(uint4*)&bF[(2*256+tid)*8] = bB2;                                        \
    *(uint4*)&bF[(3*256+tid)*8] = bB3;                                        \
  } while(0)

#define COMPUTE() do {                                                        \
    short8 ah[4], al[4], bh4[4], bl4[4];                                      \
    _Pragma("unroll")                                                         \
    for (int m=0;m<4;++m){                                                    \
      ah[m] = *(const short8*)&aF[((wr4+m)*64+lane)*8];                       \
      al[m] = *(const short8*)&aF[4096 + ((wr4+m)*64+lane)*8];                \
    }                                                                         \
    _Pragma("unroll")                                                         \
    for (int n=0;n<4;++n){                                                    \
      bh4[n] = *(const short8*)&bF[((wc4+n)*64+lane)*8];                      \
      bl4[n] = *(const short8*)&bF[4096 + ((wc4+n)*64+lane)*8];               \
    }                                                                         \
    _Pragma("unroll")                                                         \
    for (int m=0;m<4;++m)                                                     \
      _Pragma("unroll")                                                       \
      for (int n=0;n<4;++n){                                                  \
        acc[m][n] = __builtin_amdgcn_mfma_f32_16x16x32_bf16(ah[m], bh4[n], acc[m][n], 0,0,0); \
        acc[m][n] = __builtin_amdgcn_mfma_f32_16x16x32_bf16(al[m], bh4[n], acc[m][n], 0,0,0); \
        acc[m][n] = __builtin_amdgcn_mfma_f32_16x16x32_bf16(ah[m], bl4[n], acc[m][n], 0,0,0); \
      }                                                                       \
  } while(0)

  // prologue: buf <- ks0; regsA <- ks1
  LOADG_A(0);
  WRITE_A();
  LOADG_A(1);
  __syncthreads();

  for (int ks=0; ks<32; ks+=2){
    // ---- even sub-iter: compute(ks); loads for ks+2 issue under compute ----
    if (ks+2 < 32) LOADG_B(ks+2);
    COMPUTE();                       // data ks
    __syncthreads();                 // LDS reads done; loads drained (overlapped)
    WRITE_A();                       // buf <- data ks+1 (regsA)
    __syncthreads();
    // ---- odd sub-iter: compute(ks+1); loads for ks+3 under compute ----
    if (ks+3 < 32) LOADG_A(ks+3);
    COMPUTE();                       // data ks+1
    __syncthreads();
    if (ks+2 < 32) WRITE_B();        // buf <- data ks+2 (regsB)
    __syncthreads();
  }
#undef LOADG_A
#undef LOADG_B
#undef WRITE_A
#undef WRITE_B
#undef COMPUTE

  // ---- epilogue: C/D layout col=lane&15, row=(lane>>4)*4+r ----
  const int cr = (lane >> 4) * 4;
  const int cc = lane & 15;
#pragma unroll
  for (int m=0;m<4;++m)
#pragma unroll
    for (int n=0;n<4;++n){
      int row0_ = t0 + (wr4+m)*16 + cr;
      int col   = nbn*128 + (wc4+n)*16 + cc;
#pragma unroll
      for (int r=0;r<4;++r)
        h[(size_t)(row0_+r)*H_DIM + col] = acc[m][n][r];
    }
}

// ===========================================================================
// k_ln2: load h, LN + ReLU + GEMM2 + clip + L2norm + softmax + top2 + flags +
// z-partials + top-1 histogram (unflagged only). 32 tokens/block.
// ===========================================================================
__launch_bounds__(256, 3)
__global__ void k_ln2(const float* __restrict__ h,
                      const float* __restrict__ gamma,
                      const float* __restrict__ beta,
                      const float* __restrict__ W2,
                      float* __restrict__ out_rw,
                      int*   __restrict__ ti0, int* __restrict__ ti1,
                      float* __restrict__ tw0, float* __restrict__ tw1,
                      float* __restrict__ zpart,
                      int* __restrict__ flagn, int* __restrict__ flagl,
                      int* __restrict__ counts)
{
  __shared__ __align__(16) char smem[75136];
  __shared__ float zw[4];
  __shared__ int lhist[N_E];
  float* hnT  = (float*)smem;                    // [256][33] = 33792 B
  float* redS = (float*)(smem + 33792);          // [32][33]
  float* redQ = (float*)(smem + 38016);          // [32][33]
  float* sW2  = (float*)(smem + 33792);          // [128][64] = 32768 (overlaps red*)
  float* logitsL = (float*)(smem + 66560);       // [32][65]
  float* muA  = (float*)(smem + 74880);
  float* rsA  = (float*)(smem + 75008);

  const int tid  = threadIdx.x;
  const int wv   = tid >> 6;
  const int lane = tid & 63;
  const int tl   = lane & 7;
  const int cl   = lane >> 3;
  const int cbase = wv*128 + cl*16;
  const int t0 = blockIdx.x * TM;

  if (tid < N_E) lhist[tid] = 0;

  float acc[4][16];
#pragma unroll
  for (int j=0;j<4;++j)
#pragma unroll
    for (int q=0;q<4;++q)
      *(float4*)&acc[j][q*4] = *(const float4*)&h[(size_t)(t0+tl*4+j)*H_DIM + cbase + q*4];

  // ---------------- LayerNorm stats ----------------
  const int g = wv*8 + cl;
#pragma unroll
  for (int j=0;j<4;++j) {
    float s=0.f, qq=0.f;
#pragma unroll
    for (int q=0;q<16;++q){ s += acc[j][q]; qq += acc[j][q]*acc[j][q]; }
    redS[(tl*4+j)*33 + g] = s;
    redQ[(tl*4+j)*33 + g] = qq;
  }
  __syncthreads();
  if (tid < 32) {
    float s=0.f, qq=0.f;
    for (int gg=0; gg<32; ++gg){ s += redS[tid*33+gg]; qq += redQ[tid*33+gg]; }
    float mu = s * (1.f/512.f);
    float var = qq * (1.f/512.f) - mu*mu;
    muA[tid] = mu;
    rsA[tid] = rsqrtf(var + 1e-5f);
  }
  __syncthreads();

  {
    float gmv[16], btv[16];
#pragma unroll
    for (int q=0;q<4;++q){
      *(float4*)&gmv[q*4] = *(const float4*)&gamma[cbase+q*4];
      *(float4*)&btv[q*4] = *(const float4*)&beta[cbase+q*4];
    }
    float mu_[4], rs_[4];
#pragma unroll
    for (int j=0;j<4;++j){ mu_[j]=muA[tl*4+j]; rs_[j]=rsA[tl*4+j]; }
#pragma unroll
    for (int j=0;j<4;++j)
#pragma unroll
      for (int q=0;q<16;++q){
        float hv = (acc[j][q]-mu_[j])*rs_[j]*gmv[q] + btv[q];
        acc[j][q] = fmaxf(hv, 0.f);
      }
  }

  // ---------------- GEMM2 (32KB W2 stages) ----------------
  float plog[8];
#pragma unroll
  for (int i=0;i<8;++i) plog[i]=0.f;
  const int t2 = tid & 31, e0 = (tid >> 5) * 8;

  for (int p=0; p<2; ++p) {
    if ((wv>>1) == p) {
      int ccb = (wv&1)*128 + cl*16;
#pragma unroll
      for (int j=0;j<4;++j)
#pragma unroll
        for (int q=0;q<16;++q)
          hnT[(ccb+q)*33 + tl*4 + j] = acc[j][q];
    }
    __syncthreads();
    for (int ch=0; ch<2; ++ch) {
      {
        const float4* src = (const float4*)(W2 + (size_t)(p*256+ch*128)*N_E);
        float4* dst = (float4*)sW2;
#pragma unroll
        for (int i=0;i<8;++i) dst[tid + 256*i] = src[tid + 256*i];
      }
      __syncthreads();
#pragma unroll 8
      for (int kk=0; kk<128; ++kk) {
        float hh = hnT[(ch*128+kk)*33 + t2];
        float4 wa = *(const float4*)&sW2[kk*64 + e0];
        float4 wb = *(const float4*)&sW2[kk*64 + e0 + 4];
        plog[0]=fmaf(hh,wa.x,plog[0]); plog[1]=fmaf(hh,wa.y,plog[1]);
        plog[2]=fmaf(hh,wa.z,plog[2]); plog[3]=fmaf(hh,wa.w,plog[3]);
        plog[4]=fmaf(hh,wb.x,plog[4]); plog[5]=fmaf(hh,wb.y,plog[5]);
        plog[6]=fmaf(hh,wb.z,plog[6]); plog[7]=fmaf(hh,wb.w,plog[7]);
      }
      __syncthreads();
    }
  }
#pragma unroll
  for (int i=0;i<8;++i) logitsL[t2*65 + e0 + i] = plog[i];
  __syncthreads();

  // ---------------- epilogue: 8 lanes per token ----------------
  const int tE = tid >> 3, jE = tid & 7;
  float v[8];
#pragma unroll
  for (int i=0;i<8;++i){
    float z = logitsL[tE*65 + jE*8 + i];
    v[i] = fminf(fmaxf(z, -50.f), 50.f);
  }
  float ss = 0.f;
#pragma unroll
  for (int i=0;i<8;++i) ss += v[i]*v[i];
#pragma unroll
  for (int m=1;m<8;m<<=1) ss += __shfl_xor(ss, m, 8);
  float scale = 1.f/(fmaxf(sqrtf(ss), 1e-6f) + 1e-6f);
  float ln[8];
#pragma unroll
  for (int i=0;i<8;++i) ln[i] = v[i]*scale;
  float mx = -1e30f;
#pragma unroll
  for (int i=0;i<8;++i) mx = fmaxf(mx, ln[i]);
#pragma unroll
  for (int m=1;m<8;m<<=1) mx = fmaxf(mx, __shfl_xor(mx, m, 8));

  float ex[8], st=0.f, sn=0.f;
#pragma unroll
  for (int i=0;i<8;++i){
    ex[i] = expf((ln[i]-mx)*10.f);
    st += ex[i];
    sn += expf(ln[i]-mx);
  }
#pragma unroll
  for (int m=1;m<8;m<<=1){ st += __shfl_xor(st, m, 8); sn += __shfl_xor(sn, m, 8); }

  float inv_st = 1.f/st;
  float rw[8];
#pragma unroll
  for (int i=0;i<8;++i) rw[i] = ex[i]*inv_st;

  const size_t tok = (size_t)t0 + tE;
  {
    float4* o = (float4*)(out_rw + tok*N_E + jE*8);
    o[0] = make_float4(rw[0],rw[1],rw[2],rw[3]);
    o[1] = make_float4(rw[4],rw[5],rw[6],rw[7]);
  }

  float g1,g2,g3; int i1,i2;
  {
    float bv=-1e30f; int bi=1<<30;
#pragma unroll
    for (int i=0;i<8;++i){ int idx=jE*8+i;
      if (ln[i]>bv || (ln[i]==bv && idx<bi)){ bv=ln[i]; bi=idx; } }
#pragma unroll
    for (int m=1;m<8;m<<=1){ float ov=__shfl_xor(bv,m,8); int oi=__shfl_xor(bi,m,8);
      if (ov>bv || (ov==bv && oi<bi)){ bv=ov; bi=oi; } }
    g1=bv; i1=bi;
    bv=-1e30f; bi=1<<30;
#pragma unroll
    for (int i=0;i<8;++i){ int idx=jE*8+i; if (idx==i1) continue;
      if (ln[i]>bv || (ln[i]==bv && idx<bi)){ bv=ln[i]; bi=idx; } }
#pragma unroll
    for (int m=1;m<8;m<<=1){ float ov=__shfl_xor(bv,m,8); int oi=__shfl_xor(bi,m,8);
      if (ov>bv || (ov==bv && oi<bi)){ bv=ov; bi=oi; } }
    g2=bv; i2=bi;
    bv=-1e30f;
#pragma unroll
    for (int i=0;i<8;++i){ int idx=jE*8+i; if (idx==i1||idx==i2) continue;
      bv = fmaxf(bv, ln[i]); }
#pragma unroll
    for (int m=1;m<8;m<<=1) bv = fmaxf(bv, __shfl_xor(bv,m,8));
    g3=bv;
  }
  if (jE==0){
    float r1 = expf((g1-mx)*10.f)*inv_st;
    float r2 = expf((g2-mx)*10.f)*inv_st;
    float a1 = fminf(fmaxf(r1, 0.001f), 0.8f);
    float a2 = fminf(fmaxf(r2, 0.001f), 0.8f);
    float d  = fmaxf(a1+a2, 1e-6f) + 1e-6f;
    ti0[tok]=i1; ti1[tok]=i2; tw0[tok]=a1/d; tw1[tok]=a2/d;
    bool flg = ((g1-g2) < MARGIN_F) || ((g2-g3) < MARGIN_F);
    if (flg){
      int p = atomicAdd(flagn, 1);
      flagl[p] = (int)tok;
    } else {
      atomicAdd(&lhist[i1], 1);
    }
  }

  float lse = mx + logf(sn);
  float zq = 0.f;
#pragma unroll
  for (int i=0;i<8;++i){
    float lp = fminf(fmaxf(ln[i]-lse, -50.f), 50.f);
    zq += lp*lp;
  }
  zq = wred64(zq);
  if (lane==0) zw[wv] = zq;
  __syncthreads();
  if (tid==0) zpart[blockIdx.x] = zw[0]+zw[1]+zw[2]+zw[3];
  if (tid < N_E && lhist[tid] > 0) atomicAdd(&counts[tid], lhist[tid]);
}

// ===========================================================================
// FALLBACK (round-5, proven): fused f32 k_main
// ===========================================================================
__launch_bounds__(256, 3)
__global__ void k_main(const float* __restrict__ x,
                       const float* __restrict__ W1,
                       const float* __restrict__ gamma,
                       const float* __restrict__ beta,
                       const float* __restrict__ W2,
                       float* __restrict__ out_rw,
                       int*   __restrict__ ti0, int* __restrict__ ti1,
                       float* __restrict__ tw0, float* __restrict__ tw1,
                       float* __restrict__ zpart,
                       int* __restrict__ flagn, int* __restrict__ flagl)
{
  __shared__ __align__(16) char smem[53888];
  __shared__ float zw[4];
  float* sW   = (float*)smem;
  float* sX   = (float*)(smem + 32768);
  float* hnT  = (float*)smem;
  float* redS = (float*)(smem + 36864);
  float* redQ = (float*)(smem + 36864 + 4224);
  float* sW2  = (float*)(smem + 36864);
  float* logitsL = (float*)(smem + 45312);
  float* muA  = (float*)(smem + 53632);
  float* rsA  = (float*)(smem + 53760);

  const int tid  = threadIdx.x;
  const int wv   = tid >> 6;
  const int lane = tid & 63;
  const int tl   = lane & 7;
  const int cl   = lane >> 3;
  const int cbase = wv*128 + cl*16;
  const int t0 = blockIdx.x * TM;

  float acc[4][16];
#pragma unroll
  for (int j=0;j<4;++j)
#pragma unroll
    for (int q=0;q<16;++q) acc[j][q]=0.f;

  for (int k0 = 0; k0 < D_IN; k0 += BK) {
    {
      const float4* srcw = (const float4*)(W1 + (size_t)k0 * H_DIM);
      float4* dstw = (float4*)sW;
#pragma unroll
      for (int i=0;i<8;++i) dstw[tid + 256*i] = srcw[tid + 256*i];
    }
    {
      int e0 = tid*2;
      int tt = e0 >> 4, kk = e0 & 15;
      float2 xv = *(const float2*)&x[(size_t)(t0+tt)*D_IN + k0 + kk];
      sX[kk*36 + tt]     = xv.x;
      sX[(kk+1)*36 + tt] = xv.y;
    }
    __syncthreads();
#pragma unroll
    for (int kk=0; kk<BK; ++kk) {
      float4 a = *(const float4*)&sX[kk*36 + tl*4];
      float b[16];
#pragma unroll
      for (int q=0;q<4;++q) *(float4*)&b[q*4] = *(const float4*)&sW[kk*512 + cbase + q*4];
      float av[4] = {a.x, a.y, a.z, a.w};
#pragma unroll
      for (int j=0;j<4;++j)
#pragma unroll
        for (int q=0;q<16;++q)
          acc[j][q] = fmaf(av[j], b[q], acc[j][q]);
    }
    __syncthreads();
  }

  const int g = wv*8 + cl;
#pragma unroll
  for (int j=0;j<4;++j) {
    float s=0.f, qq=0.f;
#pragma unroll
    for (int q=0;q<16;++q){ s += acc[j][q]; qq += acc[j][q]*acc[j][q]; }
    redS[(tl*4+j)*33 + g] = s;
    redQ[(tl*4+j)*33 + g] = qq;
  }
  __syncthreads();
  if (tid < 32) {
    float s=0.f, qq=0.f;
    for (int gg=0; gg<32; ++gg){ s += redS[tid*33+gg]; qq += redQ[tid*33+gg]; }
    float mu = s * (1.f/512.f);
    float var = qq * (1.f/512.f) - mu*mu;
    muA[tid] = mu;
    rsA[tid] = rsqrtf(var + 1e-5f);
  }
  __syncthreads();

  {
    float gmv[16], btv[16];
#pragma unroll
    for (int q=0;q<4;++q){
      *(float4*)&gmv[q*4] = *(const float4*)&gamma[cbase+q*4];
      *(float4*)&btv[q*4] = *(const float4*)&beta[cbase+q*4];
    }
    float mu_[4], rs_[4];
#pragma unroll
    for (int j=0;j<4;++j){ mu_[j]=muA[tl*4+j]; rs_[j]=rsA[tl*4+j]; }
#pragma unroll
    for (int j=0;j<4;++j)
#pragma unroll
      for (int q=0;q<16;++q){
        float hv = (acc[j][q]-mu_[j])*rs_[j]*gmv[q] + btv[q];
        acc[j][q] = fmaxf(hv, 0.f);
      }
  }

  float plog[8];
#pragma unroll
  for (int i=0;i<8;++i) plog[i]=0.f;
  const int t2 = tid & 31, e0 = (tid >> 5) * 8;

  for (int p=0; p<2; ++p) {
    if ((wv>>1) == p) {
      int ccb = (wv&1)*128 + cl*16;
#pragma unroll
      for (int j=0;j<4;++j)
#pragma unroll
        for (int q=0;q<16;++q)
          hnT[(ccb+q)*33 + tl*4 + j] = acc[j][q];
    }
    __syncthreads();
    for (int ch=0; ch<8; ++ch) {
      {
        const float4* src = (const float4*)(W2 + (size_t)(p*256+ch*32)*N_E);
        float4* dst = (float4*)sW2;
        dst[tid]     = src[tid];
        dst[tid+256] = src[tid+256];
      }
      __syncthreads();
#pragma unroll
      for (int kk=0; kk<32; ++kk) {
        float hh = hnT[(ch*32+kk)*33 + t2];
        float4 wa = *(const float4*)&sW2[kk*64 + e0];
        float4 wb = *(const float4*)&sW2[kk*64 + e0 + 4];
        plog[0]=fmaf(hh,wa.x,plog[0]); plog[1]=fmaf(hh,wa.y,plog[1]);
        plog[2]=fmaf(hh,wa.z,plog[2]); plog[3]=fmaf(hh,wa.w,plog[3]);
        plog[4]=fmaf(hh,wb.x,plog[4]); plog[5]=fmaf(hh,wb.y,plog[5]);
        plog[6]=fmaf(hh,wb.z,plog[6]); plog[7]=fmaf(hh,wb.w,plog[7]);
      }
      __syncthreads();
    }
  }
#pragma unroll
  for (int i=0;i<8;++i) logitsL[t2*65 + e0 + i] = plog[i];
  __syncthreads();

  const int tE = tid >> 3, jE = tid & 7;
  float v[8];
#pragma unroll
  for (int i=0;i<8;++i){
    float z = logitsL[tE*65 + jE*8 + i];
    v[i] = fminf(fmaxf(z, -50.f), 50.f);
  }
  float ss = 0.f;
#pragma unroll
  for (int i=0;i<8;++i) ss += v[i]*v[i];
#pragma unroll
  for (int m=1;m<8;m<<=1) ss += __shfl_xor(ss, m, 8);
  float scale = 1.f/(fmaxf(sqrtf(ss), 1e-6f) + 1e-6f);
  float ln[8];
#pragma unroll
  for (int i=0;i<8;++i) ln[i] = v[i]*scale;
  float mx = -1e30f;
#pragma unroll
  for (int i=0;i<8;++i) mx = fmaxf(mx, ln[i]);
#pragma unroll
  for (int m=1;m<8;m<<=1) mx = fmaxf(mx, __shfl_xor(mx, m, 8));

  float ex[8], st=0.f, sn=0.f;
#pragma unroll
  for (int i=0;i<8;++i){
    ex[i] = expf((ln[i]-mx)*10.f);
    st += ex[i];
    sn += expf(ln[i]-mx);
  }
#pragma unroll
  for (int m=1;m<8;m<<=1){ st += __shfl_xor(st, m, 8); sn += __shfl_xor(sn, m, 8); }

  float inv_st = 1.f/st;
  float rw[8];
#pragma unroll
  for (int i=0;i<8;++i) rw[i] = ex[i]*inv_st;

  const size_t tok = (size_t)t0 + tE;
  {
    float4* o = (float4*)(out_rw + tok*N_E + jE*8);
    o[0] = make_float4(rw[0],rw[1],rw[2],rw[3]);
    o[1] = make_float4(rw[4],rw[5],rw[6],rw[7]);
  }

  float g1,g2,g3; int i1,i2;
  {
    float bv=-1e30f; int bi=1<<30;
#pragma unroll
    for (int i=0;i<8;++i){ int idx=jE*8+i;
      if (ln[i]>bv || (ln[i]==bv && idx<bi)){ bv=ln[i]; bi=idx; } }
#pragma unroll
    for (int m=1;m<8;m<<=1){ float ov=__shfl_xor(bv,m,8); int oi=__shfl_xor(bi,m,8);
      if (ov>bv || (ov==bv && oi<bi)){ bv=ov; bi=oi; } }
    g1=bv; i1=bi;
    bv=-1e30f; bi=1<<30;
#pragma unroll
    for (int i=0;i<8;++i){ int idx=jE*8+i; if (idx==i1) continue;
      if (ln[i]>bv || (ln[i]==bv && idx<bi)){ bv=ln[i]; bi=idx; } }
#pragma unroll
    for (int m=1;m<8;m<<=1){ float ov=__shfl_xor(bv,m,8); int oi=__shfl_xor(bi,m,8);
      if (ov>bv || (ov==bv && oi<bi)){ bv=ov; bi=oi; } }
    g2=bv; i2=bi;
    bv=-1e30f;
#pragma unroll
    for (int i=0;i<8;++i){ int idx=jE*8+i; if (idx==i1||idx==i2) continue;
      bv = fmaxf(bv, ln[i]); }
#pragma unroll
    for (int m=1;m<8;m<<=1) bv = fmaxf(bv, __shfl_xor(bv,m,8));
    g3=bv;
  }
  if (jE==0){
    float r1 = expf((g1-mx)*10.f)*inv_st;
    float r2 = expf((g2-mx)*10.f)*inv_st;
    float a1 = fminf(fmaxf(r1, 0.001f), 0.8f);
    float a2 = fminf(fmaxf(r2, 0.001f), 0.8f);
    float d  = fmaxf(a1+a2, 1e-6f) + 1e-6f;
    ti0[tok]=i1; ti1[tok]=i2; tw0[tok]=a1/d; tw1[tok]=a2/d;
    if ((g1-g2) < MARGIN || (g2-g3) < MARGIN){
      int p = atomicAdd(flagn, 1);
      flagl[p] = (int)tok;
    }
  }

  float lse = mx + logf(sn);
  float zq = 0.f;
#pragma unroll
  for (int i=0;i<8;++i){
    float lp = fminf(fmaxf(ln[i]-lse, -50.f), 50.f);
    zq += lp*lp;
  }
  zq = wred64(zq);
  if (lane==0) zw[wv] = zq;
  __syncthreads();
  if (tid==0) zpart[blockIdx.x] = zw[0]+zw[1]+zw[2]+zw[3];
}

// ===========================================================================
// np-f32 emulator for flagged tokens — LDS-staged (round-8 proven).
// ===========================================================================
__launch_bounds__(256, 1)
__global__ void k_fix(const float* __restrict__ x, const float* __restrict__ W1,
                      const float* __restrict__ gamma, const float* __restrict__ beta,
                      const float* __restrict__ W2,
                      const int* __restrict__ flagl, const int* __restrict__ flagn,
                      int* __restrict__ ti0, int* __restrict__ ti1,
                      float* __restrict__ tw0, float* __restrict__ tw1,
                      int* __restrict__ counts, int do_count)
{
  __shared__ __align__(16) float sx[D_IN];
  __shared__ __align__(16) float sW[32*H_DIM];
  __shared__ float hS[H_DIM], sqS[H_DIM], hnS[H_DIM];
  __shared__ float sq64[N_E], eS[N_E];
  __shared__ float sc[4];
  const int tid = threadIdx.x;
  const int nf = *flagn;
  for (int it = blockIdx.x; it < nf; it += gridDim.x) {
    const int tok = flagl[it];
    ((float4*)sx)[tid] = ((const float4*)(x + (size_t)tok*D_IN))[tid];
    const int c0 = tid*2;
    float h0=0.f, h1=0.f, a0=0.f, a1=0.f;
    for (int kb=0; kb<D_IN; kb+=32){
      __syncthreads();
      const float4* src = (const float4*)(W1 + (size_t)kb*H_DIM);
#pragma unroll
      for (int i=0;i<16;++i) ((float4*)sW)[tid + 256*i] = src[tid + 256*i];
      __syncthreads();
#pragma unroll 8
      for (int k=0;k<32;++k){
        float xk = sx[kb+k];
        float2 w = *(const float2*)&sW[k*H_DIM + c0];
        a0 = fmaf(xk, w.x, a0); a1 = fmaf(xk, w.y, a1);
      }
      int ke = kb + 32;
      if (ke == 384){ h0 = a0; h1 = a1; a0 = 0.f; a1 = 0.f; }
      else if (ke == 768 || ke == 1024){
        h0 = __fadd_rn(h0, a0); h1 = __fadd_rn(h1, a1); a0 = 0.f; a1 = 0.f;
      }
    }
    hS[c0]=h0; hS[c0+1]=h1;
    __syncthreads();
    if (tid==0) sc[0] = __fdiv_rn(np_sum512(hS), 512.0f);
    __syncthreads();
    float mu = sc[0];
    float d0 = __fsub_rn(h0, mu), d1 = __fsub_rn(h1, mu);
    sqS[c0]   = __fmul_rn(d0,d0);
    sqS[c0+1] = __fmul_rn(d1,d1);
    __syncthreads();
    if (tid==0){
      float var = __fdiv_rn(np_sum512(sqS), 512.0f);
      sc[1] = __fsqrt_rn(__fadd_rn(var, 1e-5f));
    }
    __syncthreads();
    float den = sc[1];
    float2 gm = *(const float2*)&gamma[c0];
    float2 bt = *(const float2*)&beta[c0];
    hnS[c0]   = fmaxf(__fadd_rn(__fmul_rn(__fdiv_rn(d0,den), gm.x), bt.x), 0.f);
    hnS[c0+1] = fmaxf(__fadd_rn(__fmul_rn(__fdiv_rn(d1,den), gm.y), bt.y), 0.f);
    float b0=0.f, b1=0.f;
    for (int half=0; half<2; ++half){
      __syncthreads();
      const float4* src = (const float4*)(W2 + (size_t)(half*256)*N_E);
#pragma unroll
      for (int i=0;i<16;++i) ((float4*)sW)[tid + 256*i] = src[tid + 256*i];
      __syncthreads();
      if (tid < N_E){
        if (half==0){
#pragma unroll 8
          for (int c=0;c<256;++c) b0 = fmaf(hnS[c], sW[c*N_E+tid], b0);
        } else {
#pragma unroll 8
          for (int c=256;c<KC1;++c) b0 = fmaf(hnS[c], sW[(c-256)*N_E+tid], b0);
#pragma unroll 8
          for (int c=KC1;c<H_DIM;++c) b1 = fmaf(hnS[c], sW[(c-256)*N_E+tid], b1);
        }
      }
    }
    float lgf = 0.f;
    if (tid < N_E){
      lgf = __fadd_rn(b0, b1);
      lgf = fminf(fmaxf(lgf, -50.f), 50.f);
      sq64[tid] = __fmul_rn(lgf, lgf);
    }
    __syncthreads();
    if (tid==0){
      float nrm = __fsqrt_rn(np_sum8acc(sq64, 64));
      sc[2] = __fadd_rn(fmaxf(nrm, 1e-6f), 1e-6f);
    }
    __syncthreads();
    if (tid < N_E){
      float nl = __fdiv_rn(lgf, sc[2]);
      float z  = __fdiv_rn(nl, 0.1f);
      float mz = z;
#pragma unroll
      for (int m=1;m<64;m<<=1) mz = fmaxf(mz, __shfl_xor(mz,m,64));
      eS[tid] = expf(__fsub_rn(z, mz));
    }
    __syncthreads();
    if (tid==0) sc[3] = np_sum8acc(eS, 64);
    __syncthreads();
    if (tid < N_E){
      float rw = __fdiv_rn(eS[tid], sc[3]);
      float bv = rw; int bi = tid;
#pragma unroll
      for (int m=1;m<64;m<<=1){ float ov=__shfl_xor(bv,m,64); int oi=__shfl_xor(bi,m,64);
        if (ov>bv || (ov==bv && oi<bi)){ bv=ov; bi=oi; } }
      float R1=bv; int I1=bi;
      bv = (tid==I1) ? -1.f : rw; bi = (tid==I1) ? (1<<30) : tid;
#pragma unroll
      for (int m=1;m<64;m<<=1){ float ov=__shfl_xor(bv,m,64); int oi=__shfl_xor(bi,m,64);
        if (ov>bv || (ov==bv && oi<bi)){ bv=ov; bi=oi; } }
      float R2=bv; int I2=bi;
      if (tid==0){
        float A1 = fminf(fmaxf(R1, 0.001f), 0.8f);
        float A2 = fminf(fmaxf(R2, 0.001f), 0.8f);
        float dd = __fadd_rn(fmaxf(__fadd_rn(A1,A2), 1e-6f), 1e-6f);
        ti0[tok]=I1; ti1[tok]=I2;
        tw0[tok]=__fdiv_rn(A1,dd); tw1[tok]=__fdiv_rn(A2,dd);
        if (do_count) atomicAdd(&counts[I1], 1);
      }
    }
    __syncthreads();
  }
}

// ---------------------------------------------------------------------------
__global__ void k_hist(const int* __restrict__ ti0, int* __restrict__ counts)
{
  __shared__ int lh[N_E];
  int tid = threadIdx.x;
  if (tid < N_E) lh[tid] = 0;
  __syncthreads();
  int i = blockIdx.x*256 + tid;
  atomicAdd(&lh[ti0[i]], 1);
  __syncthreads();
  if (tid < N_E) atomicAdd(&counts[tid], lh[tid]);
}

__global__ void k_dispatch(const int* __restrict__ ti0, const int* __restrict__ ti1,
                           const float* __restrict__ tw0, const float* __restrict__ tw1,
                           const int* __restrict__ counts,
                           float* __restrict__ out_ndm, float* __restrict__ usage)
{
  __shared__ float lus[N_E];
  int tid = threadIdx.x;
  if (tid < N_E) lus[tid] = 0.f;
  __syncthreads();
  int gid = blockIdx.x*256 + tid;
  size_t tok = gid >> 3;
  int jE = gid & 7;
  int i0 = ti0[tok], i1 = ti1[tok];
  float w0 = tw0[tok], w1 = tw1[tok];
  float w1m = (counts[i1] < CAPACITY) ? w1 : 0.f;
  float inv = 1.f / fmaxf(w0 + w1m, 1e-12f);
  float vv[8];
#pragma unroll
  for (int i=0;i<8;++i){
    int e = jE*8+i;
    vv[i] = (e==i0) ? w0*inv : (e==i1) ? w1m*inv : 0.f;
  }
  float4* o = (float4*)(out_ndm + tok*N_E + jE*8);
  o[0] = make_float4(vv[0],vv[1],vv[2],vv[3]);
  o[1] = make_float4(vv[4],vv[5],vv[6],vv[7]);
  if (jE==0){
    atomicAdd(&lus[i0], w0*inv);
    atomicAdd(&lus[i1], w1m*inv);
  }
  __syncthreads();
  if (tid < N_E) atomicAdd(&usage[tid], lus[tid]);
}

__global__ void k_final(const float* __restrict__ usage, const float* __restrict__ zpart,
                        float* __restrict__ out_loss)
{
  int e = threadIdx.x;
  float u = usage[e];
  float usum = wred64(u);
  float un = u / (fmaxf(usum, 1e-6f) + 1e-6f);
  un = fminf(fmaxf(un, 1e-6f), 1.0f);
  const float target = 1.0f/64.0f;
  float term = target * (logf(target) - logf(un + 1e-6f));
  float kl = wred64(term) * (1.0f/64.0f);
  kl = fminf(kl, 100.f);
  float zs = 0.f;
  for (int i=e; i<1024; i+=64) zs += zpart[i];
  zs = wred64(zs);
  float z = fminf(zs / (float)(T_TOK*N_E), 100.f);
  float loss = 1e-4f*z + 1e-4f*kl;
  if (isnan(loss) || isinf(loss)) loss = 0.1f;
  if (e==0) out_loss[0] = loss;
}

extern "C" void kernel_launch(void* const* d_in, const int* in_sizes, int n_in,
                              void* d_out, int out_size, void* d_ws, size_t ws_size,
                              hipStream_t stream) {
  const float* x     = (const float*)d_in[0];
  const float* W1    = (const float*)d_in[1];
  const float* gamma = (const float*)d_in[2];
  const float* beta  = (const float*)d_in[3];
  const float* W2    = (const float*)d_in[4];
  float* out = (float*)d_out;

  const bool fast = (ws_size >= WS_NEED);
  char* ws = (char*)d_ws;
  char* sb = ws + (fast ? WS_OFF : 0ull);
  int*   ti0   = (int*)(sb + WS_TI0);
  int*   ti1   = (int*)(sb + WS_TI1);
  float* tw0   = (float*)(sb + WS_TW0);
  float* tw1   = (float*)(sb + WS_TW1);
  int*   cnts  = (int*)(sb + WS_CNT);
  float* usage = (float*)(sb + WS_USG);
  int*   flagn = (int*)(sb + WS_FLAGN);
  float* zpart = (float*)(sb + WS_ZP);
  int*   flagl = (int*)(sb + WS_FLAGL);

  hipMemsetAsync(sb + WS_CNT, 0, 768, stream);

  float* out_rw   = out;
  float* out_ndm  = out + (size_t)T_TOK*N_E;
  float* out_loss = out + 2ull*T_TOK*N_E;

  if (fast) {
    float* hbuf = (float*)(ws + WS_H);
    unsigned short* W1p = (unsigned short*)(ws + WS_W1P);
    k_pack<<<512, 256, 0, stream>>>(W1, W1p);
    k_g1<<<1024, 256, 0, stream>>>(x, W1p, hbuf);
    k_ln2<<<T_TOK/TM, 256, 0, stream>>>(hbuf, gamma, beta, W2,
                                        out_rw, ti0, ti1, tw0, tw1, zpart,
                                        flagn, flagl, cnts);
    k_fix<<<1024, 256, 0, stream>>>(x, W1, gamma, beta, W2, flagl, flagn,
                                    ti0, ti1, tw0, tw1, cnts, 1);
  } else {
    k_main<<<T_TOK/TM, 256, 0, stream>>>(x, W1, gamma, beta, W2,
                                         out_rw, ti0, ti1, tw0, tw1, zpart,
                                         flagn, flagl);
    k_fix<<<1024, 256, 0, stream>>>(x, W1, gamma, beta, W2, flagl, flagn,
                                    ti0, ti1, tw0, tw1, cnts, 0);
    k_hist<<<T_TOK/256, 256, 0, stream>>>(ti0, cnts);
  }
  k_dispatch<<<(T_TOK*8)/256, 256, 0, stream>>>(ti0, ti1, tw0, tw1, cnts,
                                                out_ndm, usage);
  k_final<<<1, 64, 0, stream>>>(usage, zpart, out_loss);
}

// Round 15
// 282.210 us; speedup vs baseline: 1.1524x; 1.0516x over previous
//
#include <hip/hip_runtime.h>
#include <hip/hip_bf16.h>
#include <math.h>

// Problem constants
#define T_TOK 32768
#define D_IN  1024
#define H_DIM 512
#define N_E   64
#define TM    32
#define BK    16
#define CAPACITY 1280
#define MARGIN   2e-4f   // fallback f32 path flag margin
#define MARGIN_F 1e-4f   // MFMA 3-product path margin
#define KC1 384

// ws layout (fast path): [h: 64MB][W1p: 2MB][small block]
#define WS_H    0ull
#define WS_W1P  67108864ull
#define WS_OFF  69206016ull
#define WS_NEED 69900000ull
// small block offsets (relative)
#define WS_TI0 0
#define WS_TI1 (4*T_TOK)
#define WS_TW0 (8*T_TOK)
#define WS_TW1 (12*T_TOK)
#define WS_CNT (16*T_TOK)
#define WS_USG (WS_CNT+256)
#define WS_FLAGN (WS_USG+256)
#define WS_ZP  (WS_FLAGN+256)
#define WS_FLAGL (WS_ZP+4096)

typedef __attribute__((ext_vector_type(8))) short short8;
typedef __attribute__((ext_vector_type(4))) float f32x4;

__device__ __forceinline__ float wred64(float v){
#pragma unroll
  for (int m=1;m<64;m<<=1) v += __shfl_xor(v, m, 64);
  return v;
}
__device__ __forceinline__ unsigned short f2bf(float f){
  union { __hip_bfloat16 h; unsigned short u; } cv;
  cv.h = __float2bfloat16(f);
  return cv.u;
}
__device__ __forceinline__ float bf2f(unsigned short u){
  union { __hip_bfloat16 h; unsigned short u; } cv;
  cv.u = u;
  return __bfloat162float(cv.h);
}
// 8 floats -> packed hi uint4 + lo uint4 (bf16 split)
__device__ __forceinline__ void cvt8(const float4 A, const float4 B, uint4 &hi, uint4 &lo){
  unsigned h0=f2bf(A.x),h1=f2bf(A.y),h2=f2bf(A.z),h3=f2bf(A.w);
  unsigned h4=f2bf(B.x),h5=f2bf(B.y),h6=f2bf(B.z),h7=f2bf(B.w);
  unsigned l0=f2bf(A.x-bf2f(h0)),l1=f2bf(A.y-bf2f(h1)),l2=f2bf(A.z-bf2f(h2)),l3=f2bf(A.w-bf2f(h3));
  unsigned l4=f2bf(B.x-bf2f(h4)),l5=f2bf(B.y-bf2f(h5)),l6=f2bf(B.z-bf2f(h6)),l7=f2bf(B.w-bf2f(h7));
  hi = make_uint4(h0|(h1<<16), h2|(h3<<16), h4|(h5<<16), h6|(h7<<16));
  lo = make_uint4(l0|(l1<<16), l2|(l3<<16), l4|(l5<<16), l6|(l7<<16));
}

// ---- numpy pairwise_sum emulation (scalar path), bit-exact ----------------
__device__ __forceinline__ float np_sum8acc(const float* a, int n){
  float r0=a[0],r1=a[1],r2=a[2],r3=a[3],r4=a[4],r5=a[5],r6=a[6],r7=a[7];
  int lim = n - (n & 7);
  int i = 8;
  for (; i < lim; i += 8){
    r0=__fadd_rn(r0,a[i]);   r1=__fadd_rn(r1,a[i+1]);
    r2=__fadd_rn(r2,a[i+2]); r3=__fadd_rn(r3,a[i+3]);
    r4=__fadd_rn(r4,a[i+4]); r5=__fadd_rn(r5,a[i+5]);
    r6=__fadd_rn(r6,a[i+6]); r7=__fadd_rn(r7,a[i+7]);
  }
  float res=__fadd_rn(__fadd_rn(__fadd_rn(r0,r1),__fadd_rn(r2,r3)),
                      __fadd_rn(__fadd_rn(r4,r5),__fadd_rn(r6,r7)));
  for (; i < n; ++i) res=__fadd_rn(res,a[i]);
  return res;
}
__device__ __forceinline__ float np_sum512(const float* a){
  float s01=__fadd_rn(np_sum8acc(a,128),     np_sum8acc(a+128,128));
  float s23=__fadd_rn(np_sum8acc(a+256,128), np_sum8acc(a+384,128));
  return __fadd_rn(s01,s23);
}

// ===========================================================================
// k_pack: W1 f32 [1024][512] -> bf16 hi/lo fragment-packed for 16x16x32 MFMA.
// 512 blocks x 256 threads.
// ===========================================================================
__global__ void k_pack(const float* __restrict__ W1, unsigned short* __restrict__ W1p)
{
  int T = blockIdx.x*256 + threadIdx.x;
  int lane = T & 63;  int rest = T >> 6;
  int nt = rest & 7;  rest >>= 3;
  int s  = rest & 1;  rest >>= 1;
  int ks = rest & 31; int nb = rest >> 5;
  int n  = nb*128 + nt*16 + (lane & 15);
  int kb = ks*32 + (lane >> 4)*8;
  unsigned short o[8];
#pragma unroll
  for (int j=0;j<8;++j){
    float w = W1[(size_t)(kb+j)*H_DIM + n];
    unsigned short hi = f2bf(w);
    o[j] = s ? f2bf(w - bf2f(hi)) : hi;
  }
  size_t base = ((size_t)((((nb*32+ks)*2+s)*8+nt))*512 + (size_t)lane*8);
#pragma unroll
  for (int j=0;j<8;++j) W1p[base+j] = o[j];
}

// ===========================================================================
// k_g1: GEMM1 via MFMA bf16, 3 products. 128x128 tile, BK=32.
// ROUND-12 PROVEN VERSION (143 us, VGPR 96, 0 bank conflicts, total 282.5):
// single-buffer 32KB LDS + reg prefetch (load-early/write-late).
// Schedule experiments that all regressed: 1-barrier gload_lds (r11, 154);
// A-in-reg (r13, 195); ping-pong compute-region loads (r14, 152). The
// 2-barrier 128-sq structure is at its documented structural ceiling.
// ===========================================================================
__launch_bounds__(256, 2)
__global__ void k_g1(const float* __restrict__ x, const unsigned short* __restrict__ W1p,
                     float* __restrict__ h)
{
  __shared__ __align__(16) unsigned short aF[8192];   // hi [512 slots][8] @0, lo @4096
  __shared__ __align__(16) unsigned short bF[8192];   // hi @0, lo @4096

  const int b   = blockIdx.x;
  const int nbn = (b >> 3) & 3;
  const int bm  = (b & 7) + (b >> 5) * 8;
  const int t0  = bm * 128;

  const int tid  = threadIdx.x;
  const int lane = tid & 63;
  const int wid  = tid >> 6;
  const int wr4  = (wid >> 1) * 4;
  const int wc4  = (wid & 1) * 4;

  // A slots: s in {tid, tid+256}; row(s) = (s>>6)*16 + (s&15), g(s) = (s>>4)&3
  const int s0 = tid, s1 = tid + 256;
  const int row0 = ((s0>>6)<<4) + (s0&15);  const int g0 = (s0>>4)&3;
  const int row1 = ((s1>>6)<<4) + (s1&15);  const int g1 = (s1>>4)&3;
  const size_t xoff0 = (size_t)(t0+row0)*D_IN + g0*8;
  const size_t xoff1 = (size_t)(t0+row1)*D_IN + g1*8;

  f32x4 acc[4][4];
#pragma unroll
  for (int m=0;m<4;++m)
#pragma unroll
    for (int n=0;n<4;++n) acc[m][n] = (f32x4){0.f,0.f,0.f,0.f};

  float4 x0a, x0b, x1a, x1b;
  uint4  bb0, bb1, bb2, bb3;

#define LOADG(KS) do {                                                        \
    int k0_ = (KS)*32;                                                        \
    x0a = *(const float4*)&x[xoff0 + k0_];                                    \
    x0b = *(const float4*)&x[xoff0 + k0_ + 4];                                \
    x1a = *(const float4*)&x[xoff1 + k0_];                                    \
    x1b = *(const float4*)&x[xoff1 + k0_ + 4];                                \
    size_t ch_ = (size_t)(nbn*32 + (KS)) * 8192;                              \
    bb0 = *(const uint4*)&W1p[ch_ + (size_t)(0*256+tid)*8];                   \
    bb1 = *(const uint4*)&W1p[ch_ + (size_t)(1*256+tid)*8];                   \
    bb2 = *(const uint4*)&W1p[ch_ + (size_t)(2*256+tid)*8];                   \
    bb3 = *(const uint4*)&W1p[ch_ + (size_t)(3*256+tid)*8];                   \
  } while(0)

#define WRITE() do {                                                          \
    uint4 hi_, lo_;                                                           \
    cvt8(x0a, x0b, hi_, lo_);                                                 \
    *(uint4*)&aF[s0*8]        = hi_;                                          \
    *(uint4*)&aF[4096 + s0*8] = lo_;                                          \
    cvt8(x1a, x1b, hi_, lo_);                                                 \
    *(uint4*)&aF[s1*8]        = hi_;                                          \
    *(uint4*)&aF[4096 + s1*8] = lo_;                                          \
    *(uint4*)&bF[(0*256+tid)*8] = bb0;                                        \
    *(uint4*)&bF[(1*256+tid)*8] = bb1;                                        \
    *(uint4*)&bF[(2*256+tid)*8] = bb2;                                        \
    *(uint4*)&bF[(3*256+tid)*8] = bb3;                                        \
  } while(0)

  // prologue: buf <- ks0 data; regs <- ks1 data
  LOADG(0);
  WRITE();
  LOADG(1);
  __syncthreads();

  for (int ks=0; ks<32; ++ks){
    // ---- compute on LDS (data ks) ----
    short8 ah[4], al[4], bh4[4], bl4[4];
#pragma unroll
    for (int m=0;m<4;++m){
      ah[m] = *(const short8*)&aF[((wr4+m)*64+lane)*8];
      al[m] = *(const short8*)&aF[4096 + ((wr4+m)*64+lane)*8];
    }
#pragma unroll
    for (int n=0;n<4;++n){
      bh4[n] = *(const short8*)&bF[((wc4+n)*64+lane)*8];
      bl4[n] = *(const short8*)&bF[4096 + ((wc4+n)*64+lane)*8];
    }
#pragma unroll
    for (int m=0;m<4;++m)
#pragma unroll
      for (int n=0;n<4;++n){
        acc[m][n] = __builtin_amdgcn_mfma_f32_16x16x32_bf16(ah[m], bh4[n], acc[m][n], 0,0,0);
        acc[m][n] = __builtin_amdgcn_mfma_f32_16x16x32_bf16(al[m], bh4[n], acc[m][n], 0,0,0);
        acc[m][n] = __builtin_amdgcn_mfma_f32_16x16x32_bf16(ah[m], bl4[n], acc[m][n], 0,0,0);
      }
    __syncthreads();                 // all reads of buf(ks) done
    if (ks < 31) WRITE();            // buf <- data(ks+1) from regs
    if (ks < 30) LOADG(ks+2);        // regs <- data(ks+2), in flight over next compute
    __syncthreads();                 // writes visible
  }
#undef LOADG
#undef WRITE

  // ---- epilogue: C/D layout col=lane&15, row=(lane>>4)*4+r ----
  const int cr = (lane >> 4) * 4;
  const int cc = lane & 15;
#pragma unroll
  for (int m=0;m<4;++m)
#pragma unroll
    for (int n=0;n<4;++n){
      int row0_ = t0 + (wr4+m)*16 + cr;
      int col   = nbn*128 + (wc4+n)*16 + cc;
#pragma unroll
      for (int r=0;r<4;++r)
        h[(size_t)(row0_+r)*H_DIM + col] = acc[m][n][r];
    }
}

// ===========================================================================
// k_ln2: load h, LN + ReLU + GEMM2 + clip + L2norm + softmax + top2 + flags +
// z-partials + top-1 histogram (unflagged only). 32 tokens/block.
// GEMM2 W2 staging 32KB chunks; per-thread fmaf chain c=0..511 order UNCHANGED.
// ===========================================================================
__launch_bounds__(256, 3)
__global__ void k_ln2(const float* __restrict__ h,
                      const float* __restrict__ gamma,
                      const float* __restrict__ beta,
                      const float* __restrict__ W2,
                      float* __restrict__ out_rw,
                      int*   __restrict__ ti0, int* __restrict__ ti1,
                      float* __restrict__ tw0, float* __restrict__ tw1,
                      float* __restrict__ zpart,
                      int* __restrict__ flagn, int* __restrict__ flagl,
                      int* __restrict__ counts)
{
  __shared__ __align__(16) char smem[75136];
  __shared__ float zw[4];
  __shared__ int lhist[N_E];
  float* hnT  = (float*)smem;                    // [256][33] = 33792 B
  float* redS = (float*)(smem + 33792);          // [32][33]
  float* redQ = (float*)(smem + 38016);          // [32][33]
  float* sW2  = (float*)(smem + 33792);          // [128][64] = 32768 (overlaps red*)
  float* logitsL = (float*)(smem + 66560);       // [32][65]
  float* muA  = (float*)(smem + 74880);
  float* rsA  = (float*)(smem + 75008);

  const int tid  = threadIdx.x;
  const int wv   = tid >> 6;
  const int lane = tid & 63;
  const int tl   = lane & 7;
  const int cl   = lane >> 3;
  const int cbase = wv*128 + cl*16;
  const int t0 = blockIdx.x * TM;

  if (tid < N_E) lhist[tid] = 0;

  float acc[4][16];
#pragma unroll
  for (int j=0;j<4;++j)
#pragma unroll
    for (int q=0;q<4;++q)
      *(float4*)&acc[j][q*4] = *(const float4*)&h[(size_t)(t0+tl*4+j)*H_DIM + cbase + q*4];

  // ---------------- LayerNorm stats ----------------
  const int g = wv*8 + cl;
#pragma unroll
  for (int j=0;j<4;++j) {
    float s=0.f, qq=0.f;
#pragma unroll
    for (int q=0;q<16;++q){ s += acc[j][q]; qq += acc[j][q]*acc[j][q]; }
    redS[(tl*4+j)*33 + g] = s;
    redQ[(tl*4+j)*33 + g] = qq;
  }
  __syncthreads();
  if (tid < 32) {
    float s=0.f, qq=0.f;
    for (int gg=0; gg<32; ++gg){ s += redS[tid*33+gg]; qq += redQ[tid*33+gg]; }
    float mu = s * (1.f/512.f);
    float var = qq * (1.f/512.f) - mu*mu;
    muA[tid] = mu;
    rsA[tid] = rsqrtf(var + 1e-5f);
  }
  __syncthreads();

  {
    float gmv[16], btv[16];
#pragma unroll
    for (int q=0;q<4;++q){
      *(float4*)&gmv[q*4] = *(const float4*)&gamma[cbase+q*4];
      *(float4*)&btv[q*4] = *(const float4*)&beta[cbase+q*4];
    }
    float mu_[4], rs_[4];
#pragma unroll
    for (int j=0;j<4;++j){ mu_[j]=muA[tl*4+j]; rs_[j]=rsA[tl*4+j]; }
#pragma unroll
    for (int j=0;j<4;++j)
#pragma unroll
      for (int q=0;q<16;++q){
        float hv = (acc[j][q]-mu_[j])*rs_[j]*gmv[q] + btv[q];
        acc[j][q] = fmaxf(hv, 0.f);
      }
  }

  // ---------------- GEMM2 (32KB W2 stages; chain order preserved) ----------
  float plog[8];
#pragma unroll
  for (int i=0;i<8;++i) plog[i]=0.f;
  const int t2 = tid & 31, e0 = (tid >> 5) * 8;

  for (int p=0; p<2; ++p) {
    if ((wv>>1) == p) {
      int ccb = (wv&1)*128 + cl*16;
#pragma unroll
      for (int j=0;j<4;++j)
#pragma unroll
        for (int q=0;q<16;++q)
          hnT[(ccb+q)*33 + tl*4 + j] = acc[j][q];
    }
    __syncthreads();
    for (int ch=0; ch<2; ++ch) {
      {  // stage W2 rows [p*256+ch*128, +128): 32KB contiguous
        const float4* src = (const float4*)(W2 + (size_t)(p*256+ch*128)*N_E);
        float4* dst = (float4*)sW2;
#pragma unroll
        for (int i=0;i<8;++i) dst[tid + 256*i] = src[tid + 256*i];
      }
      __syncthreads();
#pragma unroll 8
      for (int kk=0; kk<128; ++kk) {
        float hh = hnT[(ch*128+kk)*33 + t2];
        float4 wa = *(const float4*)&sW2[kk*64 + e0];
        float4 wb = *(const float4*)&sW2[kk*64 + e0 + 4];
        plog[0]=fmaf(hh,wa.x,plog[0]); plog[1]=fmaf(hh,wa.y,plog[1]);
        plog[2]=fmaf(hh,wa.z,plog[2]); plog[3]=fmaf(hh,wa.w,plog[3]);
        plog[4]=fmaf(hh,wb.x,plog[4]); plog[5]=fmaf(hh,wb.y,plog[5]);
        plog[6]=fmaf(hh,wb.z,plog[6]); plog[7]=fmaf(hh,wb.w,plog[7]);
      }
      __syncthreads();
    }
  }
#pragma unroll
  for (int i=0;i<8;++i) logitsL[t2*65 + e0 + i] = plog[i];
  __syncthreads();

  // ---------------- epilogue: 8 lanes per token ----------------
  const int tE = tid >> 3, jE = tid & 7;
  float v[8];
#pragma unroll
  for (int i=0;i<8;++i){
    float z = logitsL[tE*65 + jE*8 + i];
    v[i] = fminf(fmaxf(z, -50.f), 50.f);
  }
  float ss = 0.f;
#pragma unroll
  for (int i=0;i<8;++i) ss += v[i]*v[i];
#pragma unroll
  for (int m=1;m<8;m<<=1) ss += __shfl_xor(ss, m, 8);
  float scale = 1.f/(fmaxf(sqrtf(ss), 1e-6f) + 1e-6f);
  float ln[8];
#pragma unroll
  for (int i=0;i<8;++i) ln[i] = v[i]*scale;
  float mx = -1e30f;
#pragma unroll
  for (int i=0;i<8;++i) mx = fmaxf(mx, ln[i]);
#pragma unroll
  for (int m=1;m<8;m<<=1) mx = fmaxf(mx, __shfl_xor(mx, m, 8));

  float ex[8], st=0.f, sn=0.f;
#pragma unroll
  for (int i=0;i<8;++i){
    ex[i] = expf((ln[i]-mx)*10.f);
    st += ex[i];
    sn += expf(ln[i]-mx);
  }
#pragma unroll
  for (int m=1;m<8;m<<=1){ st += __shfl_xor(st, m, 8); sn += __shfl_xor(sn, m, 8); }

  float inv_st = 1.f/st;
  float rw[8];
#pragma unroll
  for (int i=0;i<8;++i) rw[i] = ex[i]*inv_st;

  const size_t tok = (size_t)t0 + tE;
  {
    float4* o = (float4*)(out_rw + tok*N_E + jE*8);
    o[0] = make_float4(rw[0],rw[1],rw[2],rw[3]);
    o[1] = make_float4(rw[4],rw[5],rw[6],rw[7]);
  }

  float g1,g2,g3; int i1,i2;
  {
    float bv=-1e30f; int bi=1<<30;
#pragma unroll
    for (int i=0;i<8;++i){ int idx=jE*8+i;
      if (ln[i]>bv || (ln[i]==bv && idx<bi)){ bv=ln[i]; bi=idx; } }
#pragma unroll
    for (int m=1;m<8;m<<=1){ float ov=__shfl_xor(bv,m,8); int oi=__shfl_xor(bi,m,8);
      if (ov>bv || (ov==bv && oi<bi)){ bv=ov; bi=oi; } }
    g1=bv; i1=bi;
    bv=-1e30f; bi=1<<30;
#pragma unroll
    for (int i=0;i<8;++i){ int idx=jE*8+i; if (idx==i1) continue;
      if (ln[i]>bv || (ln[i]==bv && idx<bi)){ bv=ln[i]; bi=idx; } }
#pragma unroll
    for (int m=1;m<8;m<<=1){ float ov=__shfl_xor(bv,m,8); int oi=__shfl_xor(bi,m,8);
      if (ov>bv || (ov==bv && oi<bi)){ bv=ov; bi=oi; } }
    g2=bv; i2=bi;
    bv=-1e30f;
#pragma unroll
    for (int i=0;i<8;++i){ int idx=jE*8+i; if (idx==i1||idx==i2) continue;
      bv = fmaxf(bv, ln[i]); }
#pragma unroll
    for (int m=1;m<8;m<<=1) bv = fmaxf(bv, __shfl_xor(bv,m,8));
    g3=bv;
  }
  if (jE==0){
    float r1 = expf((g1-mx)*10.f)*inv_st;
    float r2 = expf((g2-mx)*10.f)*inv_st;
    float a1 = fminf(fmaxf(r1, 0.001f), 0.8f);
    float a2 = fminf(fmaxf(r2, 0.001f), 0.8f);
    float d  = fmaxf(a1+a2, 1e-6f) + 1e-6f;
    ti0[tok]=i1; ti1[tok]=i2; tw0[tok]=a1/d; tw1[tok]=a2/d;
    bool flg = ((g1-g2) < MARGIN_F) || ((g2-g3) < MARGIN_F);
    if (flg){
      int p = atomicAdd(flagn, 1);
      flagl[p] = (int)tok;
    } else {
      atomicAdd(&lhist[i1], 1);   // flagged tokens counted in k_fix instead
    }
  }

  float lse = mx + logf(sn);
  float zq = 0.f;
#pragma unroll
  for (int i=0;i<8;++i){
    float lp = fminf(fmaxf(ln[i]-lse, -50.f), 50.f);
    zq += lp*lp;
  }
  zq = wred64(zq);
  if (lane==0) zw[wv] = zq;
  __syncthreads();
  if (tid==0) zpart[blockIdx.x] = zw[0]+zw[1]+zw[2]+zw[3];
  if (tid < N_E && lhist[tid] > 0) atomicAdd(&counts[tid], lhist[tid]);
}

// ===========================================================================
// FALLBACK (round-5, proven): fused f32 k_main
// ===========================================================================
__launch_bounds__(256, 3)
__global__ void k_main(const float* __restrict__ x,
                       const float* __restrict__ W1,
                       const float* __restrict__ gamma,
                       const float* __restrict__ beta,
                       const float* __restrict__ W2,
                       float* __restrict__ out_rw,
                       int*   __restrict__ ti0, int* __restrict__ ti1,
                       float* __restrict__ tw0, float* __restrict__ tw1,
                       float* __restrict__ zpart,
                       int* __restrict__ flagn, int* __restrict__ flagl)
{
  __shared__ __align__(16) char smem[53888];
  __shared__ float zw[4];
  float* sW   = (float*)smem;
  float* sX   = (float*)(smem + 32768);
  float* hnT  = (float*)smem;
  float* redS = (float*)(smem + 36864);
  float* redQ = (float*)(smem + 36864 + 4224);
  float* sW2  = (float*)(smem + 36864);
  float* logitsL = (float*)(smem + 45312);
  float* muA  = (float*)(smem + 53632);
  float* rsA  = (float*)(smem + 53760);

  const int tid  = threadIdx.x;
  const int wv   = tid >> 6;
  const int lane = tid & 63;
  const int tl   = lane & 7;
  const int cl   = lane >> 3;
  const int cbase = wv*128 + cl*16;
  const int t0 = blockIdx.x * TM;

  float acc[4][16];
#pragma unroll
  for (int j=0;j<4;++j)
#pragma unroll
    for (int q=0;q<16;++q) acc[j][q]=0.f;

  for (int k0 = 0; k0 < D_IN; k0 += BK) {
    {
      const float4* srcw = (const float4*)(W1 + (size_t)k0 * H_DIM);
      float4* dstw = (float4*)sW;
#pragma unroll
      for (int i=0;i<8;++i) dstw[tid + 256*i] = srcw[tid + 256*i];
    }
    {
      int e0 = tid*2;
      int tt = e0 >> 4, kk = e0 & 15;
      float2 xv = *(const float2*)&x[(size_t)(t0+tt)*D_IN + k0 + kk];
      sX[kk*36 + tt]     = xv.x;
      sX[(kk+1)*36 + tt] = xv.y;
    }
    __syncthreads();
#pragma unroll
    for (int kk=0; kk<BK; ++kk) {
      float4 a = *(const float4*)&sX[kk*36 + tl*4];
      float b[16];
#pragma unroll
      for (int q=0;q<4;++q) *(float4*)&b[q*4] = *(const float4*)&sW[kk*512 + cbase + q*4];
      float av[4] = {a.x, a.y, a.z, a.w};
#pragma unroll
      for (int j=0;j<4;++j)
#pragma unroll
        for (int q=0;q<16;++q)
          acc[j][q] = fmaf(av[j], b[q], acc[j][q]);
    }
    __syncthreads();
  }

  const int g = wv*8 + cl;
#pragma unroll
  for (int j=0;j<4;++j) {
    float s=0.f, qq=0.f;
#pragma unroll
    for (int q=0;q<16;++q){ s += acc[j][q]; qq += acc[j][q]*acc[j][q]; }
    redS[(tl*4+j)*33 + g] = s;
    redQ[(tl*4+j)*33 + g] = qq;
  }
  __syncthreads();
  if (tid < 32) {
    float s=0.f, qq=0.f;
    for (int gg=0; gg<32; ++gg){ s += redS[tid*33+gg]; qq += redQ[tid*33+gg]; }
    float mu = s * (1.f/512.f);
    float var = qq * (1.f/512.f) - mu*mu;
    muA[tid] = mu;
    rsA[tid] = rsqrtf(var + 1e-5f);
  }
  __syncthreads();

  {
    float gmv[16], btv[16];
#pragma unroll
    for (int q=0;q<4;++q){
      *(float4*)&gmv[q*4] = *(const float4*)&gamma[cbase+q*4];
      *(float4*)&btv[q*4] = *(const float4*)&beta[cbase+q*4];
    }
    float mu_[4], rs_[4];
#pragma unroll
    for (int j=0;j<4;++j){ mu_[j]=muA[tl*4+j]; rs_[j]=rsA[tl*4+j]; }
#pragma unroll
    for (int j=0;j<4;++j)
#pragma unroll
      for (int q=0;q<16;++q){
        float hv = (acc[j][q]-mu_[j])*rs_[j]*gmv[q] + btv[q];
        acc[j][q] = fmaxf(hv, 0.f);
      }
  }

  float plog[8];
#pragma unroll
  for (int i=0;i<8;++i) plog[i]=0.f;
  const int t2 = tid & 31, e0 = (tid >> 5) * 8;

  for (int p=0; p<2; ++p) {
    if ((wv>>1) == p) {
      int ccb = (wv&1)*128 + cl*16;
#pragma unroll
      for (int j=0;j<4;++j)
#pragma unroll
        for (int q=0;q<16;++q)
          hnT[(ccb+q)*33 + tl*4 + j] = acc[j][q];
    }
    __syncthreads();
    for (int ch=0; ch<8; ++ch) {
      {
        const float4* src = (const float4*)(W2 + (size_t)(p*256+ch*32)*N_E);
        float4* dst = (float4*)sW2;
        dst[tid]     = src[tid];
        dst[tid+256] = src[tid+256];
      }
      __syncthreads();
#pragma unroll
      for (int kk=0; kk<32; ++kk) {
        float hh = hnT[(ch*32+kk)*33 + t2];
        float4 wa = *(const float4*)&sW2[kk*64 + e0];
        float4 wb = *(const float4*)&sW2[kk*64 + e0 + 4];
        plog[0]=fmaf(hh,wa.x,plog[0]); plog[1]=fmaf(hh,wa.y,plog[1]);
        plog[2]=fmaf(hh,wa.z,plog[2]); plog[3]=fmaf(hh,wa.w,plog[3]);
        plog[4]=fmaf(hh,wb.x,plog[4]); plog[5]=fmaf(hh,wb.y,plog[5]);
        plog[6]=fmaf(hh,wb.z,plog[6]); plog[7]=fmaf(hh,wb.w,plog[7]);
      }
      __syncthreads();
    }
  }
#pragma unroll
  for (int i=0;i<8;++i) logitsL[t2*65 + e0 + i] = plog[i];
  __syncthreads();

  const int tE = tid >> 3, jE = tid & 7;
  float v[8];
#pragma unroll
  for (int i=0;i<8;++i){
    float z = logitsL[tE*65 + jE*8 + i];
    v[i] = fminf(fmaxf(z, -50.f), 50.f);
  }
  float ss = 0.f;
#pragma unroll
  for (int i=0;i<8;++i) ss += v[i]*v[i];
#pragma unroll
  for (int m=1;m<8;m<<=1) ss += __shfl_xor(ss, m, 8);
  float scale = 1.f/(fmaxf(sqrtf(ss), 1e-6f) + 1e-6f);
  float ln[8];
#pragma unroll
  for (int i=0;i<8;++i) ln[i] = v[i]*scale;
  float mx = -1e30f;
#pragma unroll
  for (int i=0;i<8;++i) mx = fmaxf(mx, ln[i]);
#pragma unroll
  for (int m=1;m<8;m<<=1) mx = fmaxf(mx, __shfl_xor(mx, m, 8));

  float ex[8], st=0.f, sn=0.f;
#pragma unroll
  for (int i=0;i<8;++i){
    ex[i] = expf((ln[i]-mx)*10.f);
    st += ex[i];
    sn += expf(ln[i]-mx);
  }
#pragma unroll
  for (int m=1;m<8;m<<=1){ st += __shfl_xor(st, m, 8); sn += __shfl_xor(sn, m, 8); }

  float inv_st = 1.f/st;
  float rw[8];
#pragma unroll
  for (int i=0;i<8;++i) rw[i] = ex[i]*inv_st;

  const size_t tok = (size_t)t0 + tE;
  {
    float4* o = (float4*)(out_rw + tok*N_E + jE*8);
    o[0] = make_float4(rw[0],rw[1],rw[2],rw[3]);
    o[1] = make_float4(rw[4],rw[5],rw[6],rw[7]);
  }

  float g1,g2,g3; int i1,i2;
  {
    float bv=-1e30f; int bi=1<<30;
#pragma unroll
    for (int i=0;i<8;++i){ int idx=jE*8+i;
      if (ln[i]>bv || (ln[i]==bv && idx<bi)){ bv=ln[i]; bi=idx; } }
#pragma unroll
    for (int m=1;m<8;m<<=1){ float ov=__shfl_xor(bv,m,8); int oi=__shfl_xor(bi,m,8);
      if (ov>bv || (ov==bv && oi<bi)){ bv=ov; bi=oi; } }
    g1=bv; i1=bi;
    bv=-1e30f; bi=1<<30;
#pragma unroll
    for (int i=0;i<8;++i){ int idx=jE*8+i; if (idx==i1) continue;
      if (ln[i]>bv || (ln[i]==bv && idx<bi)){ bv=ln[i]; bi=idx; } }
#pragma unroll
    for (int m=1;m<8;m<<=1){ float ov=__shfl_xor(bv,m,8); int oi=__shfl_xor(bi,m,8);
      if (ov>bv || (ov==bv && oi<bi)){ bv=ov; bi=oi; } }
    g2=bv; i2=bi;
    bv=-1e30f;
#pragma unroll
    for (int i=0;i<8;++i){ int idx=jE*8+i; if (idx==i1||idx==i2) continue;
      bv = fmaxf(bv, ln[i]); }
#pragma unroll
    for (int m=1;m<8;m<<=1) bv = fmaxf(bv, __shfl_xor(bv,m,8));
    g3=bv;
  }
  if (jE==0){
    float r1 = expf((g1-mx)*10.f)*inv_st;
    float r2 = expf((g2-mx)*10.f)*inv_st;
    float a1 = fminf(fmaxf(r1, 0.001f), 0.8f);
    float a2 = fminf(fmaxf(r2, 0.001f), 0.8f);
    float d  = fmaxf(a1+a2, 1e-6f) + 1e-6f;
    ti0[tok]=i1; ti1[tok]=i2; tw0[tok]=a1/d; tw1[tok]=a2/d;
    if ((g1-g2) < MARGIN || (g2-g3) < MARGIN){
      int p = atomicAdd(flagn, 1);
      flagl[p] = (int)tok;
    }
  }

  float lse = mx + logf(sn);
  float zq = 0.f;
#pragma unroll
  for (int i=0;i<8;++i){
    float lp = fminf(fmaxf(ln[i]-lse, -50.f), 50.f);
    zq += lp*lp;
  }
  zq = wred64(zq);
  if (lane==0) zw[wv] = zq;
  __syncthreads();
  if (tid==0) zpart[blockIdx.x] = zw[0]+zw[1]+zw[2]+zw[3];
}

// ===========================================================================
// np-f32 emulator for flagged tokens — LDS-staged (round-8 proven).
// do_count=1 (fast path): histogram final top-1 of each flagged token.
// ===========================================================================
__launch_bounds__(256, 1)
__global__ void k_fix(const float* __restrict__ x, const float* __restrict__ W1,
                      const float* __restrict__ gamma, const float* __restrict__ beta,
                      const float* __restrict__ W2,
                      const int* __restrict__ flagl, const int* __restrict__ flagn,
                      int* __restrict__ ti0, int* __restrict__ ti1,
                      float* __restrict__ tw0, float* __restrict__ tw1,
                      int* __restrict__ counts, int do_count)
{
  __shared__ __align__(16) float sx[D_IN];
  __shared__ __align__(16) float sW[32*H_DIM];
  __shared__ float hS[H_DIM], sqS[H_DIM], hnS[H_DIM];
  __shared__ float sq64[N_E], eS[N_E];
  __shared__ float sc[4];
  const int tid = threadIdx.x;
  const int nf = *flagn;
  for (int it = blockIdx.x; it < nf; it += gridDim.x) {
    const int tok = flagl[it];
    ((float4*)sx)[tid] = ((const float4*)(x + (size_t)tok*D_IN))[tid];
    const int c0 = tid*2;
    float h0=0.f, h1=0.f, a0=0.f, a1=0.f;
    for (int kb=0; kb<D_IN; kb+=32){
      __syncthreads();
      const float4* src = (const float4*)(W1 + (size_t)kb*H_DIM);
#pragma unroll
      for (int i=0;i<16;++i) ((float4*)sW)[tid + 256*i] = src[tid + 256*i];
      __syncthreads();
#pragma unroll 8
      for (int k=0;k<32;++k){
        float xk = sx[kb+k];
        float2 w = *(const float2*)&sW[k*H_DIM + c0];
        a0 = fmaf(xk, w.x, a0); a1 = fmaf(xk, w.y, a1);
      }
      int ke = kb + 32;
      if (ke == 384){ h0 = a0; h1 = a1; a0 = 0.f; a1 = 0.f; }
      else if (ke == 768 || ke == 1024){
        h0 = __fadd_rn(h0, a0); h1 = __fadd_rn(h1, a1); a0 = 0.f; a1 = 0.f;
      }
    }
    hS[c0]=h0; hS[c0+1]=h1;
    __syncthreads();
    if (tid==0) sc[0] = __fdiv_rn(np_sum512(hS), 512.0f);
    __syncthreads();
    float mu = sc[0];
    float d0 = __fsub_rn(h0, mu), d1 = __fsub_rn(h1, mu);
    sqS[c0]   = __fmul_rn(d0,d0);
    sqS[c0+1] = __fmul_rn(d1,d1);
    __syncthreads();
    if (tid==0){
      float var = __fdiv_rn(np_sum512(sqS), 512.0f);
      sc[1] = __fsqrt_rn(__fadd_rn(var, 1e-5f));
    }
    __syncthreads();
    float den = sc[1];
    float2 gm = *(const float2*)&gamma[c0];
    float2 bt = *(const float2*)&beta[c0];
    hnS[c0]   = fmaxf(__fadd_rn(__fmul_rn(__fdiv_rn(d0,den), gm.x), bt.x), 0.f);
    hnS[c0+1] = fmaxf(__fadd_rn(__fmul_rn(__fdiv_rn(d1,den), gm.y), bt.y), 0.f);
    float b0=0.f, b1=0.f;
    for (int half=0; half<2; ++half){
      __syncthreads();
      const float4* src = (const float4*)(W2 + (size_t)(half*256)*N_E);
#pragma unroll
      for (int i=0;i<16;++i) ((float4*)sW)[tid + 256*i] = src[tid + 256*i];
      __syncthreads();
      if (tid < N_E){
        if (half==0){
#pragma unroll 8
          for (int c=0;c<256;++c) b0 = fmaf(hnS[c], sW[c*N_E+tid], b0);
        } else {
#pragma unroll 8
          for (int c=256;c<KC1;++c) b0 = fmaf(hnS[c], sW[(c-256)*N_E+tid], b0);
#pragma unroll 8
          for (int c=KC1;c<H_DIM;++c) b1 = fmaf(hnS[c], sW[(c-256)*N_E+tid], b1);
        }
      }
    }
    float lgf = 0.f;
    if (tid < N_E){
      lgf = __fadd_rn(b0, b1);
      lgf = fminf(fmaxf(lgf, -50.f), 50.f);
      sq64[tid] = __fmul_rn(lgf, lgf);
    }
    __syncthreads();
    if (tid==0){
      float nrm = __fsqrt_rn(np_sum8acc(sq64, 64));
      sc[2] = __fadd_rn(fmaxf(nrm, 1e-6f), 1e-6f);
    }
    __syncthreads();
    if (tid < N_E){
      float nl = __fdiv_rn(lgf, sc[2]);
      float z  = __fdiv_rn(nl, 0.1f);
      float mz = z;
#pragma unroll
      for (int m=1;m<64;m<<=1) mz = fmaxf(mz, __shfl_xor(mz,m,64));
      eS[tid] = expf(__fsub_rn(z, mz));
    }
    __syncthreads();
    if (tid==0) sc[3] = np_sum8acc(eS, 64);
    __syncthreads();
    if (tid < N_E){
      float rw = __fdiv_rn(eS[tid], sc[3]);
      float bv = rw; int bi = tid;
#pragma unroll
      for (int m=1;m<64;m<<=1){ float ov=__shfl_xor(bv,m,64); int oi=__shfl_xor(bi,m,64);
        if (ov>bv || (ov==bv && oi<bi)){ bv=ov; bi=oi; } }
      float R1=bv; int I1=bi;
      bv = (tid==I1) ? -1.f : rw; bi = (tid==I1) ? (1<<30) : tid;
#pragma unroll
      for (int m=1;m<64;m<<=1){ float ov=__shfl_xor(bv,m,64); int oi=__shfl_xor(bi,m,64);
        if (ov>bv || (ov==bv && oi<bi)){ bv=ov; bi=oi; } }
      float R2=bv; int I2=bi;
      if (tid==0){
        float A1 = fminf(fmaxf(R1, 0.001f), 0.8f);
        float A2 = fminf(fmaxf(R2, 0.001f), 0.8f);
        float dd = __fadd_rn(fmaxf(__fadd_rn(A1,A2), 1e-6f), 1e-6f);
        ti0[tok]=I1; ti1[tok]=I2;
        tw0[tok]=__fdiv_rn(A1,dd); tw1[tok]=__fdiv_rn(A2,dd);
        if (do_count) atomicAdd(&counts[I1], 1);
      }
    }
    __syncthreads();
  }
}

// ---------------------------------------------------------------------------
__global__ void k_hist(const int* __restrict__ ti0, int* __restrict__ counts)
{
  __shared__ int lh[N_E];
  int tid = threadIdx.x;
  if (tid < N_E) lh[tid] = 0;
  __syncthreads();
  int i = blockIdx.x*256 + tid;
  atomicAdd(&lh[ti0[i]], 1);
  __syncthreads();
  if (tid < N_E) atomicAdd(&counts[tid], lh[tid]);
}

__global__ void k_dispatch(const int* __restrict__ ti0, const int* __restrict__ ti1,
                           const float* __restrict__ tw0, const float* __restrict__ tw1,
                           const int* __restrict__ counts,
                           float* __restrict__ out_ndm, float* __restrict__ usage)
{
  __shared__ float lus[N_E];
  int tid = threadIdx.x;
  if (tid < N_E) lus[tid] = 0.f;
  __syncthreads();
  int gid = blockIdx.x*256 + tid;
  size_t tok = gid >> 3;
  int jE = gid & 7;
  int i0 = ti0[tok], i1 = ti1[tok];
  float w0 = tw0[tok], w1 = tw1[tok];
  float w1m = (counts[i1] < CAPACITY) ? w1 : 0.f;
  float inv = 1.f / fmaxf(w0 + w1m, 1e-12f);
  float vv[8];
#pragma unroll
  for (int i=0;i<8;++i){
    int e = jE*8+i;
    vv[i] = (e==i0) ? w0*inv : (e==i1) ? w1m*inv : 0.f;
  }
  float4* o = (float4*)(out_ndm + tok*N_E + jE*8);
  o[0] = make_float4(vv[0],vv[1],vv[2],vv[3]);
  o[1] = make_float4(vv[4],vv[5],vv[6],vv[7]);
  if (jE==0){
    atomicAdd(&lus[i0], w0*inv);
    atomicAdd(&lus[i1], w1m*inv);
  }
  __syncthreads();
  if (tid < N_E) atomicAdd(&usage[tid], lus[tid]);
}

__global__ void k_final(const float* __restrict__ usage, const float* __restrict__ zpart,
                        float* __restrict__ out_loss)
{
  int e = threadIdx.x;
  float u = usage[e];
  float usum = wred64(u);
  float un = u / (fmaxf(usum, 1e-6f) + 1e-6f);
  un = fminf(fmaxf(un, 1e-6f), 1.0f);
  const float target = 1.0f/64.0f;
  float term = target * (logf(target) - logf(un + 1e-6f));
  float kl = wred64(term) * (1.0f/64.0f);
  kl = fminf(kl, 100.f);
  float zs = 0.f;
  for (int i=e; i<1024; i+=64) zs += zpart[i];
  zs = wred64(zs);
  float z = fminf(zs / (float)(T_TOK*N_E), 100.f);
  float loss = 1e-4f*z + 1e-4f*kl;
  if (isnan(loss) || isinf(loss)) loss = 0.1f;
  if (e==0) out_loss[0] = loss;
}

extern "C" void kernel_launch(void* const* d_in, const int* in_sizes, int n_in,
                              void* d_out, int out_size, void* d_ws, size_t ws_size,
                              hipStream_t stream) {
  const float* x     = (const float*)d_in[0];
  const float* W1    = (const float*)d_in[1];
  const float* gamma = (const float*)d_in[2];
  const float* beta  = (const float*)d_in[3];
  const float* W2    = (const float*)d_in[4];
  float* out = (float*)d_out;

  const bool fast = (ws_size >= WS_NEED);
  char* ws = (char*)d_ws;
  char* sb = ws + (fast ? WS_OFF : 0ull);
  int*   ti0   = (int*)(sb + WS_TI0);
  int*   ti1   = (int*)(sb + WS_TI1);
  float* tw0   = (float*)(sb + WS_TW0);
  float* tw1   = (float*)(sb + WS_TW1);
  int*   cnts  = (int*)(sb + WS_CNT);
  float* usage = (float*)(sb + WS_USG);
  int*   flagn = (int*)(sb + WS_FLAGN);
  float* zpart = (float*)(sb + WS_ZP);
  int*   flagl = (int*)(sb + WS_FLAGL);

  hipMemsetAsync(sb + WS_CNT, 0, 768, stream);

  float* out_rw   = out;
  float* out_ndm  = out + (size_t)T_TOK*N_E;
  float* out_loss = out + 2ull*T_TOK*N_E;

  if (fast) {
    float* hbuf = (float*)(ws + WS_H);
    unsigned short* W1p = (unsigned short*)(ws + WS_W1P);
    k_pack<<<512, 256, 0, stream>>>(W1, W1p);
    k_g1<<<1024, 256, 0, stream>>>(x, W1p, hbuf);
    k_ln2<<<T_TOK/TM, 256, 0, stream>>>(hbuf, gamma, beta, W2,
                                        out_rw, ti0, ti1, tw0, tw1, zpart,
                                        flagn, flagl, cnts);
    k_fix<<<1024, 256, 0, stream>>>(x, W1, gamma, beta, W2, flagl, flagn,
                                    ti0, ti1, tw0, tw1, cnts, 1);
  } else {
    k_main<<<T_TOK/TM, 256, 0, stream>>>(x, W1, gamma, beta, W2,
                                         out_rw, ti0, ti1, tw0, tw1, zpart,
                                         flagn, flagl);
    k_fix<<<1024, 256, 0, stream>>>(x, W1, gamma, beta, W2, flagl, flagn,
                                    ti0, ti1, tw0, tw1, cnts, 0);
    k_hist<<<T_TOK/256, 256, 0, stream>>>(ti0, cnts);
  }
  k_dispatch<<<(T_TOK*8)/256, 256, 0, stream>>>(ti0, ti1, tw0, tw1, cnts,
                                                out_ndm, usage);
  k_final<<<1, 64, 0, stream>>>(usage, zpart, out_loss);
}